// Round 4
// baseline (554.863 us; speedup 1.0000x reference)
//
#include <hip/hip_runtime.h>
#include <hip/hip_bf16.h>

typedef unsigned short ushort_t;
typedef unsigned int uint_t;

#define LEAKYC 0.3f
#define BNEPS 1e-5f

// sizes
// B=8, CIN=128, LIN=2048, LOUT=4096, CMID=512, DM=256, NST=32
// chunked scan: 64 chunks x 64 steps over LOUT=4096

__device__ __forceinline__ ushort_t f2bf(float f){
    uint_t x = __float_as_uint(f);
    uint_t r = x + 0x7fffu + ((x >> 16) & 1u);
    return (ushort_t)(r >> 16);
}
__device__ __forceinline__ float bf2f(ushort_t u){
    return __uint_as_float(((uint_t)u) << 16);
}

// ---------------------------------------------------------------------------
// Kernel 1: deconv taps (4 branches) + leaky (branches 2-4) + z (bf16) + stats
// grid 1024 = B(8) * ltiles(32) * d(4), block 256
// ---------------------------------------------------------------------------
template<int S>
__device__ __forceinline__ void compute_otile(
    const float* __restrict__ xsm, const float* __restrict__ wsm,
    int og, int lg, float (&a0)[4][4], float (&a1)[4][4])
{
    const int wo = 4*og;
    const int xo = 4*lg;
    #pragma unroll 4
    for (int i = 0; i < 128; i++){
        float4 w0 = *(const float4*)(wsm + i*64 + wo);
        float4 w1 = *(const float4*)(wsm + 8192 + i*64 + wo);
        float4 q0 = *(const float4*)(xsm + i*68 + xo);
        float4 q1 = *(const float4*)(xsm + i*68 + xo + 4);
        float x0a[4] = {q1.x, q1.y, q1.z, q1.w};
        float cat[8] = {q0.x, q0.y, q0.z, q0.w, q1.x, q1.y, q1.z, q1.w};
        float w0a[4] = {w0.x, w0.y, w0.z, w0.w};
        float w1a[4] = {w1.x, w1.y, w1.z, w1.w};
        float x1a[4];
        #pragma unroll
        for (int j = 0; j < 4; j++)
            x1a[j] = cat[4 + j - S];   // x[l - S]
        #pragma unroll
        for (int oj = 0; oj < 4; oj++){
            #pragma unroll
            for (int lj = 0; lj < 4; lj++){
                a0[oj][lj] = fmaf(w0a[oj], x0a[lj], a0[oj][lj]);
                a1[oj][lj] = fmaf(w1a[oj], x1a[lj], a1[oj][lj]);
            }
        }
    }
}

__global__ __launch_bounds__(256) void k_deconv(
    const float* __restrict__ x,
    const float* __restrict__ w1, const float* __restrict__ b1,
    const float* __restrict__ w2, const float* __restrict__ b2,
    const float* __restrict__ w3, const float* __restrict__ b3,
    const float* __restrict__ w4, const float* __restrict__ b4,
    ushort_t* __restrict__ z, float* __restrict__ stats)
{
    __shared__ float xsm[128*68];        // x[l0-4 .. l0+64), 34.8 KB
    __shared__ float wsm[2*128*64];      // two taps, 64 KB ; reused as z-tile
    ushort_t* zt = (ushort_t*)wsm;       // 64 x 130 ushorts

    const int tx  = threadIdx.x;
    const int bid = blockIdx.x;
    const int d   = bid & 3;
    const int lt  = (bid >> 2) & 31;
    const int bb  = bid >> 7;
    const int l0  = lt * 64;
    const int p0  = lt * 128;

    const float* wd = (d==0) ? w1 : (d==1) ? w2 : (d==2) ? w3 : w4;
    const float* bd = (d==0) ? b1 : (d==1) ? b2 : (d==2) ? b3 : b4;

    // stage x tile (zero-pad l<0)
    for (int r = 0; r < 34; r++){
        int idx = r*256 + tx;
        int i  = idx / 68;
        int xi = idx - i*68;
        int l  = l0 - 4 + xi;
        float v = (l >= 0) ? x[(bb*128 + i)*2048 + l] : 0.f;
        xsm[idx] = v;
    }

    const int og = tx >> 4;   // 0..15 -> 4 o each
    const int lg = tx & 15;   // 0..15 -> 4 l each

    for (int ot = 0; ot < 2; ot++){
        __syncthreads();  // x staged / previous drain done
        // stage weights (both taps) for this o-tile of 64
        for (int r = 0; r < 32; r++){
            int idx = r*256 + tx;
            int i = idx >> 6;
            int o = idx & 63;
            const float2 wv = *(const float2*)(wd + ((i*128) + ot*64 + o)*2);
            wsm[i*64 + o]        = wv.x;
            wsm[8192 + i*64 + o] = wv.y;
        }
        __syncthreads();

        float a0[4][4] = {}, a1[4][4] = {};
        switch (d){
            case 0: compute_otile<0>(xsm, wsm, og, lg, a0, a1); break;
            case 1: compute_otile<1>(xsm, wsm, og, lg, a0, a1); break;
            case 2: compute_otile<2>(xsm, wsm, og, lg, a0, a1); break;
            default: compute_otile<4>(xsm, wsm, og, lg, a0, a1); break;
        }
        __syncthreads();   // done reading wsm; reuse as z-tile

        const float4 bq = *(const float4*)(bd + ot*64 + 4*og);
        float ba[4] = {bq.x, bq.y, bq.z, bq.w};
        #pragma unroll
        for (int oj = 0; oj < 4; oj++){
            float sumv = 0.f, sqv = 0.f;
            const int olocal = 4*og + oj;
            #pragma unroll
            for (int lj = 0; lj < 4; lj++){
                float ze, zo;
                if (d == 0){
                    ze = a0[oj][lj] + ba[oj];
                    zo = a1[oj][lj] + ba[oj];
                } else {
                    float v = a0[oj][lj] + a1[oj][lj] + ba[oj];
                    ze = (v >= 0.f) ? v : LEAKYC*v;
                    float vb = ba[oj];
                    zo = (vb >= 0.f) ? vb : LEAKYC*vb;
                }
                sumv += ze + zo;
                sqv  += ze*ze + zo*zo;
                zt[olocal*130 + 8*lg + 2*lj]     = f2bf(ze);
                zt[olocal*130 + 8*lg + 2*lj + 1] = f2bf(zo);
            }
            #pragma unroll
            for (int off = 8; off >= 1; off >>= 1){
                sumv += __shfl_xor(sumv, off);
                sqv  += __shfl_xor(sqv, off);
            }
            if (lg == 0){
                int c = d*128 + ot*64 + olocal;
                atomicAdd(&stats[c], sumv);
                atomicAdd(&stats[512 + c], sqv);
            }
        }
        __syncthreads();
        // drain z tile coalesced
        for (int r = 0; r < 16; r++){
            int idx = r*256 + tx;
            int o  = idx >> 6;
            int pp = (idx & 63) * 2;
            ushort2 v = *(const ushort2*)(zt + o*130 + pp);
            int c = d*128 + ot*64 + o;
            *(ushort2*)(z + (bb*512 + c)*4096 + p0 + pp) = v;
        }
    }
}

// ---------------------------------------------------------------------------
// Kernel 2a: per-channel BN scale/shift from stats
// ---------------------------------------------------------------------------
__global__ void k_bnstats(const float* __restrict__ stats,
                          const float* __restrict__ gamma, const float* __restrict__ beta,
                          float* __restrict__ scale, float* __restrict__ shift)
{
    int c = threadIdx.x;   // 512 threads
    const float N = 32768.f;
    float mean = stats[c] / N;
    float var  = stats[512 + c] / N - mean*mean;
    var = fmaxf(var, 0.f);
    float sc = gamma[c & 127] * rsqrtf(var + BNEPS);
    scale[c] = sc;
    shift[c] = beta[c & 127] - mean * sc;
}

// ---------------------------------------------------------------------------
// Kernel 2b: fold BN into conv weights
// ---------------------------------------------------------------------------
__global__ __launch_bounds__(256) void k_fold(
    const float* __restrict__ cw, const float* __restrict__ cb,
    const float* __restrict__ scale, const float* __restrict__ shift,
    float* __restrict__ Wf, float* __restrict__ constb)
{
    __shared__ float red[256];
    int m = blockIdx.x;
    int tx = threadIdx.x;
    int c1 = tx, c2 = tx + 256;
    float wv1 = cw[m*512 + c1], wv2 = cw[m*512 + c2];
    Wf[m*512 + c1] = wv1 * scale[c1];
    Wf[m*512 + c2] = wv2 * scale[c2];
    red[tx] = wv1*shift[c1] + wv2*shift[c2];
    __syncthreads();
    for (int s = 128; s > 0; s >>= 1){
        if (tx < s) red[tx] += red[tx + s];
        __syncthreads();
    }
    if (tx == 0) constb[m] = cb[m] + red[0];
}

// ---------------------------------------------------------------------------
// Kernel 3: 1x1 conv GEMM  u[b,m,p] = sum_c Wf[m,c]*z[b,c,p] + const[m]
// grid 512 = mt(2) * b(8) * pt(32), block 256, tile 128m x 128p, K-chunks 32
// ---------------------------------------------------------------------------
__global__ __launch_bounds__(256) void k_conv(
    const ushort_t* __restrict__ z, const float* __restrict__ Wf,
    const float* __restrict__ constb, float* __restrict__ u)
{
    __shared__ float Wl[32*132];
    __shared__ float Zl[32*132];
    const int tx  = threadIdx.x;
    const int bid = blockIdx.x;
    const int pt = bid & 31, b = (bid >> 5) & 7, mt = bid >> 8;
    const int m0 = mt*128, pbase = pt*128;
    const int mg = tx & 15, pg = tx >> 4;
    float acc[8][8] = {};
    for (int ct = 0; ct < 16; ct++){
        const int c0 = ct*32;
        __syncthreads();
        for (int r = 0; r < 16; r++){
            int idx = r*256 + tx;
            int mm = idx >> 5, cc = idx & 31;
            Wl[cc*132 + mm] = Wf[(m0+mm)*512 + c0 + cc];
        }
        for (int r = 0; r < 8; r++){
            int idx = r*256 + tx;
            int cc = idx >> 6, p2 = idx & 63;
            ushort2 v = *(const ushort2*)(z + (b*512 + c0 + cc)*4096 + pbase + 2*p2);
            Zl[cc*132 + 2*p2]     = bf2f(v.x);
            Zl[cc*132 + 2*p2 + 1] = bf2f(v.y);
        }
        __syncthreads();
        #pragma unroll 8
        for (int cc = 0; cc < 32; cc++){
            float4 wa = *(const float4*)(Wl + cc*132 + 8*mg);
            float4 wb = *(const float4*)(Wl + cc*132 + 8*mg + 4);
            float4 za = *(const float4*)(Zl + cc*132 + 8*pg);
            float4 zb = *(const float4*)(Zl + cc*132 + 8*pg + 4);
            float wv[8] = {wa.x,wa.y,wa.z,wa.w, wb.x,wb.y,wb.z,wb.w};
            float zv[8] = {za.x,za.y,za.z,za.w, zb.x,zb.y,zb.z,zb.w};
            #pragma unroll
            for (int i = 0; i < 8; i++){
                #pragma unroll
                for (int j = 0; j < 8; j++)
                    acc[i][j] = fmaf(wv[i], zv[j], acc[i][j]);
            }
        }
    }
    #pragma unroll
    for (int i = 0; i < 8; i++){
        int m = m0 + 8*mg + i;
        float cbv = constb[m];
        float* up = u + (b*256 + m)*4096 + pbase + 8*pg;
        float4 o0 = {acc[i][0]+cbv, acc[i][1]+cbv, acc[i][2]+cbv, acc[i][3]+cbv};
        float4 o1 = {acc[i][4]+cbv, acc[i][5]+cbv, acc[i][6]+cbv, acc[i][7]+cbv};
        *(float4*)up       = o0;
        *(float4*)(up + 4) = o1;
    }
}

// ---------------------------------------------------------------------------
// Kernel 4: SSM parameter prep  (dA, dA^64, 2*C*dB) per (h,n)
// ---------------------------------------------------------------------------
__global__ void k_ssmprep(const float* __restrict__ Are, const float* __restrict__ Aim,
                          const float* __restrict__ logdt,
                          const float* __restrict__ Cre, const float* __restrict__ Cim,
                          float* __restrict__ ssm)
{
    int g = blockIdx.x*256 + threadIdx.x;
    if (g >= 8192) return;
    int h = g >> 5;
    float ar = Are[g], ai = Aim[g];
    float dt = expf(logdt[h]);
    float ea = expf(dt*ar);
    float dAr = ea * cosf(dt*ai);
    float dAi = ea * sinf(dt*ai);
    float nr = dAr - 1.f, ni = dAi;
    float den = ar*ar + ai*ai;
    float dBr = (nr*ar + ni*ai) / den;
    float dBi = (ni*ar - nr*ai) / den;
    float cr = Cre[g]*dBr - Cim[g]*dBi;
    float ci = Cre[g]*dBi + Cim[g]*dBr;
    float tr = dAr, ti = dAi;
    #pragma unroll
    for (int k = 0; k < 6; k++){        // dA^64 by repeated squaring
        float t2r = tr*tr - ti*ti;
        float t2i = 2.f*tr*ti;
        tr = t2r; ti = t2i;
    }
    ssm[g]           = dAr;
    ssm[8192  + g]   = dAi;
    ssm[16384 + g]   = tr;
    ssm[24576 + g]   = ti;
    ssm[32768 + g]   = 2.f*cr;
    ssm[40960 + g]   = 2.f*ci;
}

// ---------------------------------------------------------------------------
// Kernel 5: scan pass 1 — per-chunk local end states (zero carry)
// grid 512 (256 h * 2 halves), block 256 (thread = (b',chunk))
// ---------------------------------------------------------------------------
__global__ __launch_bounds__(256) void k_scan1(
    const float* __restrict__ u, const float* __restrict__ dAr_, const float* __restrict__ dAi_,
    float* __restrict__ S)
{
    __shared__ float us[16640];   // 4 batches * 64 chunks * 65(pad)
    const int tx = threadIdx.x;
    const int h  = blockIdx.x >> 1;
    const int b0 = (blockIdx.x & 1) * 4;
    for (int r = 0; r < 16; r++){
        int q = r*256 + tx;
        int bq = q >> 10, pq = q & 1023;
        int p = pq*4;
        float4 v = *(const float4*)(u + ((b0+bq)*256 + h)*4096 + p);
        int base = bq*4160 + (p >> 6)*65 + (p & 63);
        us[base] = v.x; us[base+1] = v.y; us[base+2] = v.z; us[base+3] = v.w;
    }
    float dar[32], dai[32];
    {
        const float4* ar4 = (const float4*)(dAr_ + h*32);
        const float4* ai4 = (const float4*)(dAi_ + h*32);
        #pragma unroll
        for (int j = 0; j < 8; j++){
            float4 a = ar4[j]; dar[4*j]=a.x; dar[4*j+1]=a.y; dar[4*j+2]=a.z; dar[4*j+3]=a.w;
            float4 c = ai4[j]; dai[4*j]=c.x; dai[4*j+1]=c.y; dai[4*j+2]=c.z; dai[4*j+3]=c.w;
        }
    }
    __syncthreads();
    const int bq = tx >> 6, ch = tx & 63;
    const float* up = us + bq*4160 + ch*65;
    float sr[32] = {}, si[32] = {};
    for (int t = 0; t < 64; t++){
        float uv = up[t];
        #pragma unroll
        for (int n = 0; n < 32; n++){
            float nr = fmaf(dar[n], sr[n], uv);
            nr = fmaf(-dai[n], si[n], nr);
            float ni = dar[n]*si[n];
            ni = fmaf(dai[n], sr[n], ni);
            sr[n] = nr; si[n] = ni;
        }
    }
    float* Sp = S + (((b0+bq)*256 + h)*64 + ch)*64;
    #pragma unroll
    for (int k = 0; k < 16; k++){
        float4 v = {sr[2*k], si[2*k], sr[2*k+1], si[2*k+1]};
        *(float4*)(Sp + 4*k) = v;
    }
}

// ---------------------------------------------------------------------------
// Kernel 6: scan pass 2 — sequential carry combine over chunks; S := carry-in
// ---------------------------------------------------------------------------
__global__ __launch_bounds__(256) void k_scan2(
    float* __restrict__ S, const float* __restrict__ dATr_, const float* __restrict__ dATi_)
{
    int g = blockIdx.x*256 + threadIdx.x;   // 65536 = b(8)*h(256)*n(32)
    int n = g & 31, h = (g >> 5) & 255, b = g >> 13;
    float ar = dATr_[h*32 + n], ai = dATi_[h*32 + n];
    float cr = 0.f, ci = 0.f;
    float2* p = (float2*)(S + (b*256 + h)*4096 + 2*n);
    for (int c = 0; c < 64; c++){
        float2 t = *p;
        float2 w; w.x = cr; w.y = ci;
        *p = w;
        float nr = fmaf(ar, cr, t.x);
        nr = fmaf(-ai, ci, nr);
        float ni = fmaf(ai, cr, t.y);
        ni = fmaf(ar, ci, ni);
        cr = nr; ci = ni;
        p += 32;  // 64 floats per chunk
    }
}

// ---------------------------------------------------------------------------
// Kernel 7: scan pass 3 — replay chunks with carry-in, produce y
// grid 512, block 512 (thread-pair per item: 16 states each)
// ---------------------------------------------------------------------------
__global__ __launch_bounds__(512) void k_scan3(
    const float* __restrict__ u, const float* __restrict__ S,
    const float* __restrict__ dAr_, const float* __restrict__ dAi_,
    const float* __restrict__ cfr_, const float* __restrict__ cfi_,
    const float* __restrict__ Dp, float* __restrict__ out)
{
    __shared__ float us[16640];
    const int tx = threadIdx.x;
    const int h  = blockIdx.x >> 1;
    const int b0 = (blockIdx.x & 1) * 4;
    for (int r = 0; r < 8; r++){
        int q = r*512 + tx;
        int bq = q >> 10, pq = q & 1023;
        int p = pq*4;
        float4 v = *(const float4*)(u + ((b0+bq)*256 + h)*4096 + p);
        int base = bq*4160 + (p >> 6)*65 + (p & 63);
        us[base] = v.x; us[base+1] = v.y; us[base+2] = v.z; us[base+3] = v.w;
    }
    const int item = tx >> 1, nh = tx & 1;
    const int bq = item >> 6, ch = item & 63;
    const int nb = h*32 + nh*16;
    float dar[16], dai[16], cfr[16], cfi[16];
    {
        const float4* a4 = (const float4*)(dAr_ + nb);
        const float4* b4 = (const float4*)(dAi_ + nb);
        const float4* c4 = (const float4*)(cfr_ + nb);
        const float4* d4 = (const float4*)(cfi_ + nb);
        #pragma unroll
        for (int j = 0; j < 4; j++){
            float4 a = a4[j]; dar[4*j]=a.x; dar[4*j+1]=a.y; dar[4*j+2]=a.z; dar[4*j+3]=a.w;
            float4 bv= b4[j]; dai[4*j]=bv.x; dai[4*j+1]=bv.y; dai[4*j+2]=bv.z; dai[4*j+3]=bv.w;
            float4 c = c4[j]; cfr[4*j]=c.x; cfr[4*j+1]=c.y; cfr[4*j+2]=c.z; cfr[4*j+3]=c.w;
            float4 e = d4[j]; cfi[4*j]=e.x; cfi[4*j+1]=e.y; cfi[4*j+2]=e.z; cfi[4*j+3]=e.w;
        }
    }
    float sr[16], si[16];
    const float* Sp = S + (((b0+bq)*256 + h)*64 + ch)*64 + nh*32;
    #pragma unroll
    for (int k = 0; k < 8; k++){
        float4 v = *(const float4*)(Sp + 4*k);
        sr[2*k] = v.x; si[2*k] = v.y; sr[2*k+1] = v.z; si[2*k+1] = v.w;
    }
    float Dh = Dp[h];
    __syncthreads();
    float* up = us + bq*4160 + ch*65;
    for (int t = 0; t < 64; t++){
        float uv = up[t];
        float acc = 0.f;
        #pragma unroll
        for (int n = 0; n < 16; n++){
            float nr = fmaf(dar[n], sr[n], uv);
            nr = fmaf(-dai[n], si[n], nr);
            float ni = dar[n]*si[n];
            ni = fmaf(dai[n], sr[n], ni);
            sr[n] = nr; si[n] = ni;
            acc = fmaf(cfr[n], nr, acc);
            acc = fmaf(-cfi[n], ni, acc);
        }
        acc += __shfl_xor(acc, 1);
        up[t] = fmaf(Dh, uv, acc);   // overwrite u slot with y (both lanes, same value)
    }
    __syncthreads();
    for (int r = 0; r < 8; r++){
        int q = r*512 + tx;
        int bq2 = q >> 10, pq = q & 1023;
        int p = pq*4;
        int base = bq2*4160 + (p >> 6)*65 + (p & 63);
        float4 v = {us[base], us[base+1], us[base+2], us[base+3]};
        *(float4*)(out + ((b0+bq2)*256 + h)*4096 + p) = v;
    }
}

// ---------------------------------------------------------------------------
extern "C" void kernel_launch(void* const* d_in, const int* in_sizes, int n_in,
                              void* d_out, int out_size, void* d_ws, size_t ws_size,
                              hipStream_t stream)
{
    (void)in_sizes; (void)n_in; (void)out_size; (void)ws_size;
    const float* x     = (const float*)d_in[0];
    const float* w1    = (const float*)d_in[1];
    const float* b1    = (const float*)d_in[2];
    const float* w2    = (const float*)d_in[3];
    const float* b2    = (const float*)d_in[4];
    const float* w3    = (const float*)d_in[5];
    const float* b3    = (const float*)d_in[6];
    const float* w4    = (const float*)d_in[7];
    const float* b4    = (const float*)d_in[8];
    const float* gamma = (const float*)d_in[9];
    const float* beta  = (const float*)d_in[10];
    const float* cw    = (const float*)d_in[11];
    const float* cb    = (const float*)d_in[12];
    const float* Are   = (const float*)d_in[13];
    const float* Aim   = (const float*)d_in[14];
    const float* logdt = (const float*)d_in[15];
    const float* Cre   = (const float*)d_in[16];
    const float* Cim   = (const float*)d_in[17];
    const float* Dp    = (const float*)d_in[18];
    float* out = (float*)d_out;

    char* ws = (char*)d_ws;
    ushort_t* z = (ushort_t*)ws;                 // 33,554,432 B (bf16 z)
    float* u    = (float*)(ws + 33554432);       // 33,554,432 B (f32 u)
    float* S    = (float*)ws;                    // alias z: chunk states after z consumed
    float* msc  = (float*)(ws + 67108864);
    float* stats  = msc;                 // 1024 f32 (sum | sumsq)
    float* scale  = msc + 1024;          // 512
    float* shift  = msc + 1536;          // 512
    float* Wf     = msc + 2048;          // 131072
    float* constb = msc + 133120;        // 256
    float* ssm    = msc + 133376;        // 49152
    float* dAr  = ssm;
    float* dAi  = ssm + 8192;
    float* dATr = ssm + 16384;
    float* dATi = ssm + 24576;
    float* cfr  = ssm + 32768;
    float* cfi  = ssm + 40960;

    hipMemsetAsync(stats, 0, 1024*sizeof(float), stream);
    k_deconv<<<1024, 256, 0, stream>>>(x, w1,b1, w2,b2, w3,b3, w4,b4, z, stats);
    k_bnstats<<<1, 512, 0, stream>>>(stats, gamma, beta, scale, shift);
    k_fold<<<256, 256, 0, stream>>>(cw, cb, scale, shift, Wf, constb);
    k_conv<<<512, 256, 0, stream>>>(z, Wf, constb, u);
    k_ssmprep<<<32, 256, 0, stream>>>(Are, Aim, logdt, Cre, Cim, ssm);
    k_scan1<<<512, 256, 0, stream>>>(u, dAr, dAi, S);
    k_scan2<<<256, 256, 0, stream>>>(S, dATr, dATi);
    k_scan3<<<512, 512, 0, stream>>>(u, S, dAr, dAi, cfr, cfi, Dp, out);
}

// Round 7
// 371.973 us; speedup vs baseline: 1.4917x; 1.4917x over previous
//
#include <hip/hip_runtime.h>
#include <hip/hip_bf16.h>

typedef unsigned short ushort_t;
typedef unsigned int uint_t;
typedef __attribute__((ext_vector_type(8))) short bf16x8;
typedef __attribute__((ext_vector_type(4))) float f32x4;

#define LEAKYC 0.3f
#define BNEPS 1e-5f

// sizes: B=8, CIN=128, LIN=2048, LOUT=4096, CMID=512, DM=256, NST=32
// scan: 64 chunks x 64 steps over LOUT=4096

__device__ __forceinline__ ushort_t f2bf(float f){
    uint_t x = __float_as_uint(f);
    uint_t r = x + 0x7fffu + ((x >> 16) & 1u);
    return (ushort_t)(r >> 16);
}
__device__ __forceinline__ uint_t pack2(float a, float b){
    return (uint_t)f2bf(a) | ((uint_t)f2bf(b) << 16);
}

// ---------------------------------------------------------------------------
// Kernel 1: deconv taps + leaky + zT (bf16, [b][p][c] layout) + BN stats
// grid 1024 = B(8) * ltiles(32) * d(4), block 256
// chunked-K staging: LDS = 8.7KB x + 32KB w = 41.5KB -> 3 blocks/CU
// ---------------------------------------------------------------------------
template<int S>
__device__ __forceinline__ void dconv_main(
    const float* __restrict__ x, const float* __restrict__ wd,
    float* __restrict__ xsm, float* __restrict__ wsm,
    int bb, int l0, int og, int lg, int tx,
    float (&a0)[8][4], float (&a1)[8][4])
{
    for (int ic = 0; ic < 4; ic++){
        __syncthreads();
        // stage x chunk: 32 i x 68 l
        for (int rr = 0; rr < 9; rr++){
            int idx = rr*256 + tx;
            if (idx < 2176){
                int i  = idx / 68;
                int xi = idx - i*68;
                int l  = l0 - 4 + xi;
                xsm[idx] = (l >= 0) ? x[(bb*128 + ic*32 + i)*2048 + l] : 0.f;
            }
        }
        // stage w chunk: 32 i x 128 o x 2 taps  (layout [i][tap][o])
        for (int rr = 0; rr < 16; rr++){
            int idx = rr*256 + tx;
            int i = idx >> 7, o = idx & 127;
            float2 wv = *(const float2*)(wd + ((ic*32 + i)*128 + o)*2);
            wsm[i*256 + o]       = wv.x;
            wsm[i*256 + 128 + o] = wv.y;
        }
        __syncthreads();
        for (int i = 0; i < 32; i++){
            float4 wA0 = *(const float4*)(wsm + i*256 + og*8);
            float4 wA1 = *(const float4*)(wsm + i*256 + og*8 + 4);
            float4 wB0 = *(const float4*)(wsm + i*256 + 128 + og*8);
            float4 wB1 = *(const float4*)(wsm + i*256 + 128 + og*8 + 4);
            float4 q0  = *(const float4*)(xsm + i*68 + 4*lg);
            float4 q1  = *(const float4*)(xsm + i*68 + 4*lg + 4);
            float cat[8] = {q0.x,q0.y,q0.z,q0.w,q1.x,q1.y,q1.z,q1.w};
            float x0a[4] = {q1.x,q1.y,q1.z,q1.w};
            float x1a[4];
            #pragma unroll
            for (int j = 0; j < 4; j++)
                x1a[j] = cat[4 + j - S];          // x[l - S], compile-time S
            float w0a[8] = {wA0.x,wA0.y,wA0.z,wA0.w,wA1.x,wA1.y,wA1.z,wA1.w};
            float w1a[8] = {wB0.x,wB0.y,wB0.z,wB0.w,wB1.x,wB1.y,wB1.z,wB1.w};
            #pragma unroll
            for (int k = 0; k < 8; k++){
                #pragma unroll
                for (int j = 0; j < 4; j++){
                    a0[k][j] = fmaf(w0a[k], x0a[j], a0[k][j]);
                    a1[k][j] = fmaf(w1a[k], x1a[j], a1[k][j]);
                }
            }
        }
    }
}

__global__ __launch_bounds__(256) void k_deconv(
    const float* __restrict__ x,
    const float* __restrict__ w1, const float* __restrict__ b1,
    const float* __restrict__ w2, const float* __restrict__ b2,
    const float* __restrict__ w3, const float* __restrict__ b3,
    const float* __restrict__ w4, const float* __restrict__ b4,
    ushort_t* __restrict__ zT, float* __restrict__ stats)
{
    __shared__ float xsm[32*68];     // 8704 B
    __shared__ float wsm[32*256];    // 32768 B
    const int tx  = threadIdx.x;
    const int bid = blockIdx.x;
    const int d   = bid & 3;
    const int lt  = (bid >> 2) & 31;
    const int bb  = bid >> 7;
    const int l0  = lt * 64;
    const int p0  = lt * 128;
    const int og  = tx >> 4;     // 0..15 -> 8 o each
    const int lg  = tx & 15;     // 0..15 -> 4 l each (x2 parity)

    const float* wd = (d==0) ? w1 : (d==1) ? w2 : (d==2) ? w3 : w4;
    const float* bd = (d==0) ? b1 : (d==1) ? b2 : (d==2) ? b3 : b4;

    float a0[8][4] = {}, a1[8][4] = {};
    switch (d){
        case 0:  dconv_main<0>(x, wd, xsm, wsm, bb, l0, og, lg, tx, a0, a1); break;
        case 1:  dconv_main<1>(x, wd, xsm, wsm, bb, l0, og, lg, tx, a0, a1); break;
        case 2:  dconv_main<2>(x, wd, xsm, wsm, bb, l0, og, lg, tx, a0, a1); break;
        default: dconv_main<4>(x, wd, xsm, wsm, bb, l0, og, lg, tx, a0, a1); break;
    }

    // epilogue: bias + leaky + bf16 pack + stats
    const float4 bq0 = *(const float4*)(bd + og*8);
    const float4 bq1 = *(const float4*)(bd + og*8 + 4);
    float bias[8] = {bq0.x,bq0.y,bq0.z,bq0.w,bq1.x,bq1.y,bq1.z,bq1.w};
    float zoc[8];
    #pragma unroll
    for (int k = 0; k < 8; k++){
        float vb = bias[k];
        zoc[k] = (vb >= 0.f) ? vb : LEAKYC*vb;   // odd-position const for d>0
    }

    float sums[8] = {}, sqs[8] = {};
    const size_t zbase = ((size_t)(bb*4096 + p0 + 8*lg))*512 + d*128 + og*8;
    #pragma unroll
    for (int lj = 0; lj < 4; lj++){
        float ze[8], zo[8];
        #pragma unroll
        for (int k = 0; k < 8; k++){
            if (d == 0){
                ze[k] = a0[k][lj] + bias[k];
                zo[k] = a1[k][lj] + bias[k];
            } else {
                float v = a0[k][lj] + a1[k][lj] + bias[k];
                ze[k] = (v >= 0.f) ? v : LEAKYC*v;
                zo[k] = zoc[k];
            }
            sums[k] += ze[k] + zo[k];
            sqs[k]  += ze[k]*ze[k] + zo[k]*zo[k];
        }
        uint4 ve = {pack2(ze[0],ze[1]), pack2(ze[2],ze[3]), pack2(ze[4],ze[5]), pack2(ze[6],ze[7])};
        uint4 vo = {pack2(zo[0],zo[1]), pack2(zo[2],zo[3]), pack2(zo[4],zo[5]), pack2(zo[6],zo[7])};
        *(uint4*)(zT + zbase + (size_t)(2*lj)*512)     = ve;
        *(uint4*)(zT + zbase + (size_t)(2*lj + 1)*512) = vo;
    }
    #pragma unroll
    for (int off = 8; off >= 1; off >>= 1){
        #pragma unroll
        for (int k = 0; k < 8; k++){
            sums[k] += __shfl_xor(sums[k], off);
            sqs[k]  += __shfl_xor(sqs[k],  off);
        }
    }
    if (lg == 0){
        #pragma unroll
        for (int k = 0; k < 8; k++){
            int c = d*128 + og*8 + k;
            atomicAdd(&stats[c], sums[k]);
            atomicAdd(&stats[512 + c], sqs[k]);
        }
    }
}

// ---------------------------------------------------------------------------
// Kernel 2a: per-channel BN scale/shift from stats
// ---------------------------------------------------------------------------
__global__ void k_bnstats(const float* __restrict__ stats,
                          const float* __restrict__ gamma, const float* __restrict__ beta,
                          float* __restrict__ scale, float* __restrict__ shift)
{
    int c = threadIdx.x;   // 512 threads
    const float N = 32768.f;
    float mean = stats[c] / N;
    float var  = stats[512 + c] / N - mean*mean;
    var = fmaxf(var, 0.f);
    float sc = gamma[c & 127] * rsqrtf(var + BNEPS);
    scale[c] = sc;
    shift[c] = beta[c & 127] - mean * sc;
}

// ---------------------------------------------------------------------------
// Kernel 2b: fold BN into conv weights (bf16 output)
// ---------------------------------------------------------------------------
__global__ __launch_bounds__(256) void k_fold(
    const float* __restrict__ cw, const float* __restrict__ cb,
    const float* __restrict__ scale, const float* __restrict__ shift,
    ushort_t* __restrict__ Wfbf, float* __restrict__ constb)
{
    __shared__ float red[256];
    int m = blockIdx.x;
    int tx = threadIdx.x;
    int c1 = tx, c2 = tx + 256;
    float wv1 = cw[m*512 + c1], wv2 = cw[m*512 + c2];
    Wfbf[m*512 + c1] = f2bf(wv1 * scale[c1]);
    Wfbf[m*512 + c2] = f2bf(wv2 * scale[c2]);
    red[tx] = wv1*shift[c1] + wv2*shift[c2];
    __syncthreads();
    for (int s = 128; s > 0; s >>= 1){
        if (tx < s) red[tx] += red[tx + s];
        __syncthreads();
    }
    if (tx == 0) constb[m] = cb[m] + red[0];
}

// ---------------------------------------------------------------------------
// Kernel 3: 1x1 conv GEMM via bf16 MFMA
// u[b,m,p] = sum_c Wf[m,c]*z[c,p] + const[m];  zT layout [b][p][c] (k-major)
// grid 512 = mt(2) * b(8) * pt(32), block 256 = 4 waves (2m x 2p of 64x64)
// 16x16x32 bf16 MFMA; LDS rows padded to 40 ushorts (2-way read = free)
// ---------------------------------------------------------------------------
__global__ __launch_bounds__(256) void k_conv(
    const ushort_t* __restrict__ zT, const ushort_t* __restrict__ Wfbf,
    const float* __restrict__ constb, float* __restrict__ u)
{
    __shared__ ushort_t As[128*40];   // 10240 B  Wf[m][k-chunk]
    __shared__ ushort_t Bs[128*40];   // 10240 B  zT[p][k-chunk]
    const int tx  = threadIdx.x;
    const int bid = blockIdx.x;
    const int pt = bid & 31, b = (bid >> 5) & 7, mt = bid >> 8;
    const int m0 = mt*128, pbase = pt*128;
    const int lane = tx & 63, wvid = tx >> 6;
    const int r = lane & 15, q = lane >> 4;
    const int wm = (wvid & 1)*64, wp = (wvid >> 1)*64;

    const int smm = tx >> 1;          // 0..127
    const int skk = (tx & 1) * 16;    // 0 or 16

    const ushort_t* gA = Wfbf + (m0 + smm)*512 + skk;
    const ushort_t* gB = zT + ((size_t)(b*4096 + pbase + smm))*512 + skk;

    f32x4 acc[4][4] = {};
    uint4 ra0, ra1, rb0, rb1;
    ra0 = *(const uint4*)(gA);     ra1 = *(const uint4*)(gA + 8);
    rb0 = *(const uint4*)(gB);     rb1 = *(const uint4*)(gB + 8);

    for (int ct = 0; ct < 16; ct++){
        __syncthreads();
        *(uint4*)(&As[smm*40 + skk])     = ra0;
        *(uint4*)(&As[smm*40 + skk + 8]) = ra1;
        *(uint4*)(&Bs[smm*40 + skk])     = rb0;
        *(uint4*)(&Bs[smm*40 + skk + 8]) = rb1;
        __syncthreads();
        if (ct < 15){
            const ushort_t* gA2 = gA + (ct+1)*32;
            const ushort_t* gB2 = gB + (ct+1)*32;
            ra0 = *(const uint4*)(gA2); ra1 = *(const uint4*)(gA2 + 8);
            rb0 = *(const uint4*)(gB2); rb1 = *(const uint4*)(gB2 + 8);
        }
        bf16x8 af[4], bfv[4];
        #pragma unroll
        for (int f = 0; f < 4; f++){
            af[f]  = *(const bf16x8*)(&As[(wm + f*16 + r)*40 + 8*q]);
            bfv[f] = *(const bf16x8*)(&Bs[(wp + f*16 + r)*40 + 8*q]);
        }
        #pragma unroll
        for (int i = 0; i < 4; i++){
            #pragma unroll
            for (int j = 0; j < 4; j++){
                acc[i][j] = __builtin_amdgcn_mfma_f32_16x16x32_bf16(af[i], bfv[j], acc[i][j], 0, 0, 0);
            }
        }
    }
    // epilogue: D[row=4q+t][col=r] per fragment (verified C/D layout)
    #pragma unroll
    for (int i = 0; i < 4; i++){
        #pragma unroll
        for (int t = 0; t < 4; t++){
            int m = m0 + wm + i*16 + 4*q + t;
            float cbv = constb[m];
            float* up = u + ((size_t)(b*256 + m))*4096 + pbase + wp + r;
            #pragma unroll
            for (int j = 0; j < 4; j++)
                up[j*16] = acc[i][j][t] + cbv;
        }
    }
}

// ---------------------------------------------------------------------------
// Kernel 4: SSM parameter prep  (dA, dA^64, 2*C*dB) per (h,n)
// ---------------------------------------------------------------------------
__global__ void k_ssmprep(const float* __restrict__ Are, const float* __restrict__ Aim,
                          const float* __restrict__ logdt,
                          const float* __restrict__ Cre, const float* __restrict__ Cim,
                          float* __restrict__ ssm)
{
    int g = blockIdx.x*256 + threadIdx.x;
    if (g >= 8192) return;
    int h = g >> 5;
    float ar = Are[g], ai = Aim[g];
    float dt = expf(logdt[h]);
    float ea = expf(dt*ar);
    float dAr = ea * cosf(dt*ai);
    float dAi = ea * sinf(dt*ai);
    float nr = dAr - 1.f, ni = dAi;
    float den = ar*ar + ai*ai;
    float dBr = (nr*ar + ni*ai) / den;
    float dBi = (ni*ar - nr*ai) / den;
    float cr = Cre[g]*dBr - Cim[g]*dBi;
    float ci = Cre[g]*dBi + Cim[g]*dBr;
    float tr = dAr, ti = dAi;
    #pragma unroll
    for (int k = 0; k < 6; k++){        // dA^64 by repeated squaring
        float t2r = tr*tr - ti*ti;
        float t2i = 2.f*tr*ti;
        tr = t2r; ti = t2i;
    }
    ssm[g]           = dAr;
    ssm[8192  + g]   = dAi;
    ssm[16384 + g]   = tr;
    ssm[24576 + g]   = ti;
    ssm[32768 + g]   = 2.f*cr;
    ssm[40960 + g]   = 2.f*ci;
}

// ---------------------------------------------------------------------------
// Kernel 5: scan pass 1 — per-chunk local end states (zero carry)
// ---------------------------------------------------------------------------
__global__ __launch_bounds__(256) void k_scan1(
    const float* __restrict__ u, const float* __restrict__ dAr_, const float* __restrict__ dAi_,
    float* __restrict__ S)
{
    __shared__ float us[16640];   // 4 batches * 64 chunks * 65(pad)
    const int tx = threadIdx.x;
    const int h  = blockIdx.x >> 1;
    const int b0 = (blockIdx.x & 1) * 4;
    for (int r = 0; r < 16; r++){
        int qq = r*256 + tx;
        int bq = qq >> 10, pq = qq & 1023;
        int p = pq*4;
        float4 v = *(const float4*)(u + ((size_t)((b0+bq)*256 + h))*4096 + p);
        int base = bq*4160 + (p >> 6)*65 + (p & 63);
        us[base] = v.x; us[base+1] = v.y; us[base+2] = v.z; us[base+3] = v.w;
    }
    float dar[32], dai[32];
    {
        const float4* ar4 = (const float4*)(dAr_ + h*32);
        const float4* ai4 = (const float4*)(dAi_ + h*32);
        #pragma unroll
        for (int j = 0; j < 8; j++){
            float4 a = ar4[j]; dar[4*j]=a.x; dar[4*j+1]=a.y; dar[4*j+2]=a.z; dar[4*j+3]=a.w;
            float4 c = ai4[j]; dai[4*j]=c.x; dai[4*j+1]=c.y; dai[4*j+2]=c.z; dai[4*j+3]=c.w;
        }
    }
    __syncthreads();
    const int bq = tx >> 6, ch = tx & 63;
    const float* up = us + bq*4160 + ch*65;
    float sr[32] = {}, si[32] = {};
    for (int t = 0; t < 64; t++){
        float uv = up[t];
        #pragma unroll
        for (int n = 0; n < 32; n++){
            float nr = fmaf(dar[n], sr[n], uv);
            nr = fmaf(-dai[n], si[n], nr);
            float ni = dar[n]*si[n];
            ni = fmaf(dai[n], sr[n], ni);
            sr[n] = nr; si[n] = ni;
        }
    }
    float* Sp = S + (((size_t)((b0+bq)*256 + h))*64 + ch)*64;
    #pragma unroll
    for (int k = 0; k < 16; k++){
        float4 v = {sr[2*k], si[2*k], sr[2*k+1], si[2*k+1]};
        *(float4*)(Sp + 4*k) = v;
    }
}

// ---------------------------------------------------------------------------
// Kernel 6: scan pass 2 — sequential carry combine; S := carry-in
// ---------------------------------------------------------------------------
__global__ __launch_bounds__(256) void k_scan2(
    float* __restrict__ S, const float* __restrict__ dATr_, const float* __restrict__ dATi_)
{
    int g = blockIdx.x*256 + threadIdx.x;   // 65536 = b(8)*h(256)*n(32)
    int n = g & 31, h = (g >> 5) & 255, b = g >> 13;
    float ar = dATr_[h*32 + n], ai = dATi_[h*32 + n];
    float cr = 0.f, ci = 0.f;
    float2* p = (float2*)(S + ((size_t)(b*256 + h))*4096 + 2*n);
    for (int c = 0; c < 64; c++){
        float2 t = *p;
        float2 w; w.x = cr; w.y = ci;
        *p = w;
        float nr = fmaf(ar, cr, t.x);
        nr = fmaf(-ai, ci, nr);
        float ni = fmaf(ai, cr, t.y);
        ni = fmaf(ar, ci, ni);
        cr = nr; ci = ni;
        p += 32;  // 64 floats per chunk
    }
}

// ---------------------------------------------------------------------------
// Kernel 7: scan pass 3 — replay chunks with carry-in, produce y
// ---------------------------------------------------------------------------
__global__ __launch_bounds__(512) void k_scan3(
    const float* __restrict__ u, const float* __restrict__ S,
    const float* __restrict__ dAr_, const float* __restrict__ dAi_,
    const float* __restrict__ cfr_, const float* __restrict__ cfi_,
    const float* __restrict__ Dp, float* __restrict__ out)
{
    __shared__ float us[16640];
    const int tx = threadIdx.x;
    const int h  = blockIdx.x >> 1;
    const int b0 = (blockIdx.x & 1) * 4;
    for (int r = 0; r < 8; r++){
        int qq = r*512 + tx;
        int bq = qq >> 10, pq = qq & 1023;
        int p = pq*4;
        float4 v = *(const float4*)(u + ((size_t)((b0+bq)*256 + h))*4096 + p);
        int base = bq*4160 + (p >> 6)*65 + (p & 63);
        us[base] = v.x; us[base+1] = v.y; us[base+2] = v.z; us[base+3] = v.w;
    }
    const int item = tx >> 1, nh = tx & 1;
    const int bq = item >> 6, ch = item & 63;
    const int nb = h*32 + nh*16;
    float dar[16], dai[16], cfr[16], cfi[16];
    {
        const float4* a4 = (const float4*)(dAr_ + nb);
        const float4* b4 = (const float4*)(dAi_ + nb);
        const float4* c4 = (const float4*)(cfr_ + nb);
        const float4* d4 = (const float4*)(cfi_ + nb);
        #pragma unroll
        for (int j = 0; j < 4; j++){
            float4 a = a4[j]; dar[4*j]=a.x; dar[4*j+1]=a.y; dar[4*j+2]=a.z; dar[4*j+3]=a.w;
            float4 bv= b4[j]; dai[4*j]=bv.x; dai[4*j+1]=bv.y; dai[4*j+2]=bv.z; dai[4*j+3]=bv.w;
            float4 c = c4[j]; cfr[4*j]=c.x; cfr[4*j+1]=c.y; cfr[4*j+2]=c.z; cfr[4*j+3]=c.w;
            float4 e = d4[j]; cfi[4*j]=e.x; cfi[4*j+1]=e.y; cfi[4*j+2]=e.z; cfi[4*j+3]=e.w;
        }
    }
    float sr[16], si[16];
    const float* Sp = S + (((size_t)((b0+bq)*256 + h))*64 + ch)*64 + nh*32;
    #pragma unroll
    for (int k = 0; k < 8; k++){
        float4 v = *(const float4*)(Sp + 4*k);
        sr[2*k] = v.x; si[2*k] = v.y; sr[2*k+1] = v.z; si[2*k+1] = v.w;
    }
    float Dh = Dp[h];
    __syncthreads();
    float* up = us + bq*4160 + ch*65;
    for (int t = 0; t < 64; t++){
        float uv = up[t];
        float acc = 0.f;
        #pragma unroll
        for (int n = 0; n < 16; n++){
            float nr = fmaf(dar[n], sr[n], uv);
            nr = fmaf(-dai[n], si[n], nr);
            float ni = dar[n]*si[n];
            ni = fmaf(dai[n], sr[n], ni);
            sr[n] = nr; si[n] = ni;
            acc = fmaf(cfr[n], nr, acc);
            acc = fmaf(-cfi[n], ni, acc);
        }
        acc += __shfl_xor(acc, 1);
        up[t] = fmaf(Dh, uv, acc);
    }
    __syncthreads();
    for (int r = 0; r < 8; r++){
        int qq = r*512 + tx;
        int bq2 = qq >> 10, pq = qq & 1023;
        int p = pq*4;
        int base = bq2*4160 + (p >> 6)*65 + (p & 63);
        float4 v = {us[base], us[base+1], us[base+2], us[base+3]};
        *(float4*)(out + ((size_t)((b0+bq2)*256 + h))*4096 + p) = v;
    }
}

// ---------------------------------------------------------------------------
extern "C" void kernel_launch(void* const* d_in, const int* in_sizes, int n_in,
                              void* d_out, int out_size, void* d_ws, size_t ws_size,
                              hipStream_t stream)
{
    (void)in_sizes; (void)n_in; (void)out_size; (void)ws_size;
    const float* x     = (const float*)d_in[0];
    const float* w1    = (const float*)d_in[1];
    const float* b1    = (const float*)d_in[2];
    const float* w2    = (const float*)d_in[3];
    const float* b2    = (const float*)d_in[4];
    const float* w3    = (const float*)d_in[5];
    const float* b3    = (const float*)d_in[6];
    const float* w4    = (const float*)d_in[7];
    const float* b4    = (const float*)d_in[8];
    const float* gamma = (const float*)d_in[9];
    const float* beta  = (const float*)d_in[10];
    const float* cw    = (const float*)d_in[11];
    const float* cb    = (const float*)d_in[12];
    const float* Are   = (const float*)d_in[13];
    const float* Aim   = (const float*)d_in[14];
    const float* logdt = (const float*)d_in[15];
    const float* Cre   = (const float*)d_in[16];
    const float* Cim   = (const float*)d_in[17];
    const float* Dp    = (const float*)d_in[18];
    float* out = (float*)d_out;

    char* ws = (char*)d_ws;
    ushort_t* zT = (ushort_t*)ws;                // 33,554,432 B  bf16 z^T [b][p][c]
    float* u     = (float*)(ws + 33554432);      // 33,554,432 B  f32 u
    float* S     = (float*)ws;                   // alias zT after conv consumes it
    char* mscB   = ws + 67108864;
    float* stats   = (float*)(mscB + 0);         // 1024 f32
    float* scale   = (float*)(mscB + 4096);      // 512
    float* shift   = (float*)(mscB + 6144);      // 512
    float* constb  = (float*)(mscB + 8192);      // 256
    ushort_t* Wfbf = (ushort_t*)(mscB + 9216);   // 131072 ushort (256x512 bf16)
    float* ssm     = (float*)(mscB + 271360);    // 49152 f32
    float* dAr  = ssm;
    float* dAi  = ssm + 8192;
    float* dATr = ssm + 16384;
    float* dATi = ssm + 24576;
    float* cfr  = ssm + 32768;
    float* cfi  = ssm + 40960;

    hipMemsetAsync(stats, 0, 1024*sizeof(float), stream);
    k_deconv<<<1024, 256, 0, stream>>>(x, w1,b1, w2,b2, w3,b3, w4,b4, zT, stats);
    k_bnstats<<<1, 512, 0, stream>>>(stats, gamma, beta, scale, shift);
    k_fold<<<256, 256, 0, stream>>>(cw, cb, scale, shift, Wfbf, constb);
    k_conv<<<512, 256, 0, stream>>>(zT, Wfbf, constb, u);
    k_ssmprep<<<32, 256, 0, stream>>>(Are, Aim, logdt, Cre, Cim, ssm);
    k_scan1<<<512, 256, 0, stream>>>(u, dAr, dAi, S);
    k_scan2<<<256, 256, 0, stream>>>(S, dATr, dATi);
    k_scan3<<<512, 512, 0, stream>>>(u, S, dAr, dAi, cfr, cfi, Dp, out);
}

// Round 11
// 283.172 us; speedup vs baseline: 1.9595x; 1.3136x over previous
//
#include <hip/hip_runtime.h>
#include <hip/hip_bf16.h>

typedef unsigned short ushort_t;
typedef unsigned int uint_t;
typedef __attribute__((ext_vector_type(8))) short bf16x8;
typedef __attribute__((ext_vector_type(4))) float f32x4;

#define LEAKYC 0.3f
#define BNEPS 1e-5f

// sizes: B=8, CIN=128, LIN=2048, LOUT=4096, CMID=512, DM=256, NST=32

__device__ __forceinline__ ushort_t f2bf(float f){
    uint_t x = __float_as_uint(f);
    uint_t r = x + 0x7fffu + ((x >> 16) & 1u);
    return (ushort_t)(r >> 16);
}
__device__ __forceinline__ float bf2f(ushort_t u){
    return __uint_as_float(((uint_t)u) << 16);
}
__device__ __forceinline__ uint_t pack2(float a, float b){
    return (uint_t)f2bf(a) | ((uint_t)f2bf(b) << 16);
}
__device__ __forceinline__ float lrelu(float v){
    return (v >= 0.f) ? v : LEAKYC*v;
}

// ---------------------------------------------------------------------------
// Kernel 0: weight prep — fp32 w[d][i][o][tap] -> bf16 Wt[(d*2+tap)][o][i]
// grid 128 x 256 (one thread per (i,o,t) over 32768, all 4 d)
// ---------------------------------------------------------------------------
__global__ __launch_bounds__(256) void k_wprep(
    const float* __restrict__ w1, const float* __restrict__ w2,
    const float* __restrict__ w3, const float* __restrict__ w4,
    ushort_t* __restrict__ Wt)
{
    int g = blockIdx.x*256 + threadIdx.x;    // = i*256 + o*2 + t
    int i = g >> 8, o = (g >> 1) & 127, t = g & 1;
    int ob = (t*128 + o)*128 + i;            // t*16384 + o*128 + i
    Wt[ob]             = f2bf(w1[g]);
    Wt[2*16384 + ob]   = f2bf(w2[g]);
    Wt[4*16384 + ob]   = f2bf(w3[g]);
    Wt[6*16384 + ob]   = f2bf(w4[g]);
}

// ---------------------------------------------------------------------------
// Kernel 1: deconv via bf16 MFMA.  block = (bb, lt of 32 l), 4 waves = 4 d.
// wave d: A = Wt rows (o), B = x cols (l) gathered from LDS [i][l] (stride 41),
// tap shift = read B at column l - dil/2 for the tap1 K-half.
// D: row=o, col=l (HW-verified mapping). Odd rows d>0 = leaky(bias) consts.
// ---------------------------------------------------------------------------
__global__ __launch_bounds__(256) void k_deconv(
    const float* __restrict__ x, const ushort_t* __restrict__ Wt,
    const float* __restrict__ b1, const float* __restrict__ b2,
    const float* __restrict__ b3, const float* __restrict__ b4,
    ushort_t* __restrict__ zT)
{
    __shared__ float xs[128*41];     // [i][4+l], cols 0..3 halo, 20992 B
    const int tx = threadIdx.x, lane = tx & 63;
    const int d  = tx >> 6;
    const int bb = blockIdx.x >> 6, lt = blockIdx.x & 63;
    const int l0 = lt*32;
    const float* xb = x + (size_t)bb*262144;

    for (int it = 0; it < 16; it++){         // main 128 i x 32 l
        int idx = it*256 + tx;
        int i = idx >> 5, lc = idx & 31;
        xs[i*41 + 4 + lc] = xb[i*2048 + l0 + lc];
    }
    for (int it = 0; it < 2; it++){          // halo 128 i x 4
        int idx = it*256 + tx;
        int i = idx >> 2, dl = idx & 3;
        int l = l0 - 4 + dl;
        xs[i*41 + dl] = (l >= 0) ? xb[i*2048 + l] : 0.f;
    }
    __syncthreads();

    const int r = lane & 15, q = lane >> 4;
    const int S  = (d==0) ? 0 : (1 << (d-1));
    const int NT = (d==0) ? 4 : 2;
    const float* bd = (d==0) ? b1 : (d==1) ? b2 : (d==2) ? b3 : b4;
    const size_t zrowb = (size_t)bb*4096 + (size_t)lt*64;

    for (int tt = 0; tt < NT; tt++){
        const int ob   = (d==0) ? ((tt&1)*64) : tt*64;
        const int tapA = (d==0) ? (tt>>1) : 0;
        const int nseg = (d==0) ? 1 : 2;
        f32x4 acc[4][2] = {};
        for (int sg = 0; sg < nseg; sg++){
            const int tap = (d==0) ? tapA : sg;
            const int sh  = (sg==1) ? S : 0;
            const ushort_t* Arow = Wt + ((size_t)((d*2+tap)*128 + ob + r))*128 + q*8;
            const float* xcolb = xs + 4 + r - sh;
            #pragma unroll
            for (int kc = 0; kc < 4; kc++){
                uint4 a4[4];
                #pragma unroll
                for (int mi = 0; mi < 4; mi++)
                    a4[mi] = *(const uint4*)(Arow + mi*2048 + kc*32);
                const int kb = kc*32 + q*8;
                uint_t bfr[2][4];
                #pragma unroll
                for (int nj = 0; nj < 2; nj++){
                    const float* xc = xcolb + nj*16;
                    #pragma unroll
                    for (int kk = 0; kk < 4; kk++){
                        float e0 = xc[(kb + 2*kk)*41];
                        float e1 = xc[(kb + 2*kk + 1)*41];
                        bfr[nj][kk] = pack2(e0, e1);
                    }
                }
                #pragma unroll
                for (int mi = 0; mi < 4; mi++){
                    #pragma unroll
                    for (int nj = 0; nj < 2; nj++){
                        acc[mi][nj] = __builtin_amdgcn_mfma_f32_16x16x32_bf16(
                            *(const bf16x8*)&a4[mi], *(const bf16x8*)bfr[nj],
                            acc[mi][nj], 0, 0, 0);
                    }
                }
            }
        }
        // epilogue: + bias, leaky (d>0 only), pack, 8B store into zT[p][c]
        const int podd = (d==0 && tapA==1) ? 1 : 0;
        #pragma unroll
        for (int mi = 0; mi < 4; mi++){
            const int oo = ob + mi*16 + q*4;
            const float4 bq = *(const float4*)(bd + oo);
            const int c = d*128 + oo;
            #pragma unroll
            for (int nj = 0; nj < 2; nj++){
                f32x4 v = acc[mi][nj];
                float z0 = v[0] + bq.x, z1 = v[1] + bq.y;
                float z2 = v[2] + bq.z, z3 = v[3] + bq.w;
                if (d > 0){
                    z0 = lrelu(z0); z1 = lrelu(z1);
                    z2 = lrelu(z2); z3 = lrelu(z3);
                }
                const int lcol = nj*16 + r;
                size_t row = zrowb + 2*lcol + podd;
                uint2 pk = { pack2(z0, z1), pack2(z2, z3) };
                *(uint2*)(zT + row*512 + c) = pk;
            }
        }
    }

    // d>0: odd positions are channel constants leaky(bias)
    if (d > 0){
        #pragma unroll
        for (int rep = 0; rep < 8; rep++){
            int idx = rep*64 + lane;
            int li = idx >> 4, cg = (idx & 15)*8;
            float4 f0 = *(const float4*)(bd + cg);
            float4 f1 = *(const float4*)(bd + cg + 4);
            uint4 pkv = { pack2(lrelu(f0.x), lrelu(f0.y)),
                          pack2(lrelu(f0.z), lrelu(f0.w)),
                          pack2(lrelu(f1.x), lrelu(f1.y)),
                          pack2(lrelu(f1.z), lrelu(f1.w)) };
            size_t row = zrowb + 2*li + 1;
            *(uint4*)(zT + row*512 + d*128 + cg) = pkv;
        }
    }
}

// ---------------------------------------------------------------------------
// Kernel 1b: BN stats from zT (bf16) — coalesced column sums
// grid 256 x 256: block = 128 p-rows, thread = 2 channels
// ---------------------------------------------------------------------------
__global__ __launch_bounds__(256) void k_stats(
    const ushort_t* __restrict__ zT, float* __restrict__ stats)
{
    const int tx = threadIdx.x;
    const int c = 2*tx;
    const ushort_t* base = zT + (size_t)blockIdx.x*128*512 + c;
    float s0=0.f, s1=0.f, q0=0.f, q1=0.f;
    for (int rr = 0; rr < 128; rr++){
        ushort2 v = *(const ushort2*)(base + (size_t)rr*512);
        float f0 = bf2f(v.x), f1 = bf2f(v.y);
        s0 += f0; s1 += f1;
        q0 += f0*f0; q1 += f1*f1;
    }
    atomicAdd(&stats[c],       s0);
    atomicAdd(&stats[c+1],     s1);
    atomicAdd(&stats[512+c],   q0);
    atomicAdd(&stats[512+c+1], q1);
}

// ---------------------------------------------------------------------------
// Kernel 2a: per-channel BN scale/shift from stats  (unchanged, verified)
// ---------------------------------------------------------------------------
__global__ void k_bnstats(const float* __restrict__ stats,
                          const float* __restrict__ gamma, const float* __restrict__ beta,
                          float* __restrict__ scale, float* __restrict__ shift)
{
    int c = threadIdx.x;   // 512 threads
    const float N = 32768.f;
    float mean = stats[c] / N;
    float var  = stats[512 + c] / N - mean*mean;
    var = fmaxf(var, 0.f);
    float sc = gamma[c & 127] * rsqrtf(var + BNEPS);
    scale[c] = sc;
    shift[c] = beta[c & 127] - mean * sc;
}

// ---------------------------------------------------------------------------
// Kernel 2b: fold BN into conv weights (bf16 output)  (unchanged, verified)
// ---------------------------------------------------------------------------
__global__ __launch_bounds__(256) void k_fold(
    const float* __restrict__ cw, const float* __restrict__ cb,
    const float* __restrict__ scale, const float* __restrict__ shift,
    ushort_t* __restrict__ Wfbf, float* __restrict__ constb)
{
    __shared__ float red[256];
    int m = blockIdx.x;
    int tx = threadIdx.x;
    int c1 = tx, c2 = tx + 256;
    float wv1 = cw[m*512 + c1], wv2 = cw[m*512 + c2];
    Wfbf[m*512 + c1] = f2bf(wv1 * scale[c1]);
    Wfbf[m*512 + c2] = f2bf(wv2 * scale[c2]);
    red[tx] = wv1*shift[c1] + wv2*shift[c2];
    __syncthreads();
    for (int s = 128; s > 0; s >>= 1){
        if (tx < s) red[tx] += red[tx + s];
        __syncthreads();
    }
    if (tx == 0) constb[m] = cb[m] + red[0];
}

// ---------------------------------------------------------------------------
// Kernel 3: 1x1 conv GEMM via bf16 MFMA  (unchanged, verified round 7)
// ---------------------------------------------------------------------------
__global__ __launch_bounds__(256) void k_conv(
    const ushort_t* __restrict__ zT, const ushort_t* __restrict__ Wfbf,
    const float* __restrict__ constb, float* __restrict__ u)
{
    __shared__ ushort_t As[128*40];
    __shared__ ushort_t Bs[128*40];
    const int tx  = threadIdx.x;
    const int bid = blockIdx.x;
    const int pt = bid & 31, b = (bid >> 5) & 7, mt = bid >> 8;
    const int m0 = mt*128, pbase = pt*128;
    const int lane = tx & 63, wvid = tx >> 6;
    const int r = lane & 15, q = lane >> 4;
    const int wm = (wvid & 1)*64, wp = (wvid >> 1)*64;

    const int smm = tx >> 1;
    const int skk = (tx & 1) * 16;

    const ushort_t* gA = Wfbf + (m0 + smm)*512 + skk;
    const ushort_t* gB = zT + ((size_t)(b*4096 + pbase + smm))*512 + skk;

    f32x4 acc[4][4] = {};
    uint4 ra0, ra1, rb0, rb1;
    ra0 = *(const uint4*)(gA);     ra1 = *(const uint4*)(gA + 8);
    rb0 = *(const uint4*)(gB);     rb1 = *(const uint4*)(gB + 8);

    for (int ct = 0; ct < 16; ct++){
        __syncthreads();
        *(uint4*)(&As[smm*40 + skk])     = ra0;
        *(uint4*)(&As[smm*40 + skk + 8]) = ra1;
        *(uint4*)(&Bs[smm*40 + skk])     = rb0;
        *(uint4*)(&Bs[smm*40 + skk + 8]) = rb1;
        __syncthreads();
        if (ct < 15){
            const ushort_t* gA2 = gA + (ct+1)*32;
            const ushort_t* gB2 = gB + (ct+1)*32;
            ra0 = *(const uint4*)(gA2); ra1 = *(const uint4*)(gA2 + 8);
            rb0 = *(const uint4*)(gB2); rb1 = *(const uint4*)(gB2 + 8);
        }
        bf16x8 af[4], bfv[4];
        #pragma unroll
        for (int f = 0; f < 4; f++){
            af[f]  = *(const bf16x8*)(&As[(wm + f*16 + r)*40 + 8*q]);
            bfv[f] = *(const bf16x8*)(&Bs[(wp + f*16 + r)*40 + 8*q]);
        }
        #pragma unroll
        for (int i = 0; i < 4; i++){
            #pragma unroll
            for (int j = 0; j < 4; j++){
                acc[i][j] = __builtin_amdgcn_mfma_f32_16x16x32_bf16(af[i], bfv[j], acc[i][j], 0, 0, 0);
            }
        }
    }
    #pragma unroll
    for (int i = 0; i < 4; i++){
        #pragma unroll
        for (int t = 0; t < 4; t++){
            int m = m0 + wm + i*16 + 4*q + t;
            float cbv = constb[m];
            float* up = u + ((size_t)(b*256 + m))*4096 + pbase + wp + r;
            #pragma unroll
            for (int j = 0; j < 4; j++)
                up[j*16] = acc[i][j][t] + cbv;
        }
    }
}

// ---------------------------------------------------------------------------
// Kernel 4: SSM parameter prep  (unchanged, verified)
// ---------------------------------------------------------------------------
__global__ void k_ssmprep(const float* __restrict__ Are, const float* __restrict__ Aim,
                          const float* __restrict__ logdt,
                          const float* __restrict__ Cre, const float* __restrict__ Cim,
                          float* __restrict__ ssm)
{
    int g = blockIdx.x*256 + threadIdx.x;
    if (g >= 8192) return;
    int h = g >> 5;
    float ar = Are[g], ai = Aim[g];
    float dt = expf(logdt[h]);
    float ea = expf(dt*ar);
    float dAr = ea * cosf(dt*ai);
    float dAi = ea * sinf(dt*ai);
    float nr = dAr - 1.f, ni = dAi;
    float den = ar*ar + ai*ai;
    float dBr = (nr*ar + ni*ai) / den;
    float dBi = (ni*ar - nr*ai) / den;
    float cr = Cre[g]*dBr - Cim[g]*dBi;
    float ci = Cre[g]*dBi + Cim[g]*dBr;
    float tr = dAr, ti = dAi;
    #pragma unroll
    for (int k = 0; k < 6; k++){
        float t2r = tr*tr - ti*ti;
        float t2i = 2.f*tr*ti;
        tr = t2r; ti = t2i;
    }
    ssm[g]           = dAr;
    ssm[8192  + g]   = dAi;
    ssm[16384 + g]   = tr;
    ssm[24576 + g]   = ti;
    ssm[32768 + g]   = 2.f*cr;
    ssm[40960 + g]   = 2.f*ci;
}

// ---------------------------------------------------------------------------
// Kernel 5: scan pass 1  (unchanged, verified)
// ---------------------------------------------------------------------------
__global__ __launch_bounds__(256) void k_scan1(
    const float* __restrict__ u, const float* __restrict__ dAr_, const float* __restrict__ dAi_,
    float* __restrict__ S)
{
    __shared__ float us[16640];
    const int tx = threadIdx.x;
    const int h  = blockIdx.x >> 1;
    const int b0 = (blockIdx.x & 1) * 4;
    for (int r = 0; r < 16; r++){
        int qq = r*256 + tx;
        int bq = qq >> 10, pq = qq & 1023;
        int p = pq*4;
        float4 v = *(const float4*)(u + ((size_t)((b0+bq)*256 + h))*4096 + p);
        int base = bq*4160 + (p >> 6)*65 + (p & 63);
        us[base] = v.x; us[base+1] = v.y; us[base+2] = v.z; us[base+3] = v.w;
    }
    float dar[32], dai[32];
    {
        const float4* ar4 = (const float4*)(dAr_ + h*32);
        const float4* ai4 = (const float4*)(dAi_ + h*32);
        #pragma unroll
        for (int j = 0; j < 8; j++){
            float4 a = ar4[j]; dar[4*j]=a.x; dar[4*j+1]=a.y; dar[4*j+2]=a.z; dar[4*j+3]=a.w;
            float4 c = ai4[j]; dai[4*j]=c.x; dai[4*j+1]=c.y; dai[4*j+2]=c.z; dai[4*j+3]=c.w;
        }
    }
    __syncthreads();
    const int bq = tx >> 6, ch = tx & 63;
    const float* up = us + bq*4160 + ch*65;
    float sr[32] = {}, si[32] = {};
    for (int t = 0; t < 64; t++){
        float uv = up[t];
        #pragma unroll
        for (int n = 0; n < 32; n++){
            float nr = fmaf(dar[n], sr[n], uv);
            nr = fmaf(-dai[n], si[n], nr);
            float ni = dar[n]*si[n];
            ni = fmaf(dai[n], sr[n], ni);
            sr[n] = nr; si[n] = ni;
        }
    }
    float* Sp = S + (((size_t)((b0+bq)*256 + h))*64 + ch)*64;
    #pragma unroll
    for (int k = 0; k < 16; k++){
        float4 v = {sr[2*k], si[2*k], sr[2*k+1], si[2*k+1]};
        *(float4*)(Sp + 4*k) = v;
    }
}

// ---------------------------------------------------------------------------
// Kernel 6: scan pass 2  (unchanged, verified)
// ---------------------------------------------------------------------------
__global__ __launch_bounds__(256) void k_scan2(
    float* __restrict__ S, const float* __restrict__ dATr_, const float* __restrict__ dATi_)
{
    int g = blockIdx.x*256 + threadIdx.x;
    int n = g & 31, h = (g >> 5) & 255, b = g >> 13;
    float ar = dATr_[h*32 + n], ai = dATi_[h*32 + n];
    float cr = 0.f, ci = 0.f;
    float2* p = (float2*)(S + ((size_t)(b*256 + h))*4096 + 2*n);
    for (int c = 0; c < 64; c++){
        float2 t = *p;
        float2 w; w.x = cr; w.y = ci;
        *p = w;
        float nr = fmaf(ar, cr, t.x);
        nr = fmaf(-ai, ci, nr);
        float ni = fmaf(ai, cr, t.y);
        ni = fmaf(ar, ci, ni);
        cr = nr; ci = ni;
        p += 32;
    }
}

// ---------------------------------------------------------------------------
// Kernel 7: scan pass 3  (unchanged, verified)
// ---------------------------------------------------------------------------
__global__ __launch_bounds__(512) void k_scan3(
    const float* __restrict__ u, const float* __restrict__ S,
    const float* __restrict__ dAr_, const float* __restrict__ dAi_,
    const float* __restrict__ cfr_, const float* __restrict__ cfi_,
    const float* __restrict__ Dp, float* __restrict__ out)
{
    __shared__ float us[16640];
    const int tx = threadIdx.x;
    const int h  = blockIdx.x >> 1;
    const int b0 = (blockIdx.x & 1) * 4;
    for (int r = 0; r < 8; r++){
        int qq = r*512 + tx;
        int bq = qq >> 10, pq = qq & 1023;
        int p = pq*4;
        float4 v = *(const float4*)(u + ((size_t)((b0+bq)*256 + h))*4096 + p);
        int base = bq*4160 + (p >> 6)*65 + (p & 63);
        us[base] = v.x; us[base+1] = v.y; us[base+2] = v.z; us[base+3] = v.w;
    }
    const int item = tx >> 1, nh = tx & 1;
    const int bq = item >> 6, ch = item & 63;
    const int nb = h*32 + nh*16;
    float dar[16], dai[16], cfr[16], cfi[16];
    {
        const float4* a4 = (const float4*)(dAr_ + nb);
        const float4* b4 = (const float4*)(dAi_ + nb);
        const float4* c4 = (const float4*)(cfr_ + nb);
        const float4* d4 = (const float4*)(cfi_ + nb);
        #pragma unroll
        for (int j = 0; j < 4; j++){
            float4 a = a4[j]; dar[4*j]=a.x; dar[4*j+1]=a.y; dar[4*j+2]=a.z; dar[4*j+3]=a.w;
            float4 bv= b4[j]; dai[4*j]=bv.x; dai[4*j+1]=bv.y; dai[4*j+2]=bv.z; dai[4*j+3]=bv.w;
            float4 c = c4[j]; cfr[4*j]=c.x; cfr[4*j+1]=c.y; cfr[4*j+2]=c.z; cfr[4*j+3]=c.w;
            float4 e = d4[j]; cfi[4*j]=e.x; cfi[4*j+1]=e.y; cfi[4*j+2]=e.z; cfi[4*j+3]=e.w;
        }
    }
    float sr[16], si[16];
    const float* Sp = S + (((size_t)((b0+bq)*256 + h))*64 + ch)*64 + nh*32;
    #pragma unroll
    for (int k = 0; k < 8; k++){
        float4 v = *(const float4*)(Sp + 4*k);
        sr[2*k] = v.x; si[2*k] = v.y; sr[2*k+1] = v.z; si[2*k+1] = v.w;
    }
    float Dh = Dp[h];
    __syncthreads();
    float* up = us + bq*4160 + ch*65;
    for (int t = 0; t < 64; t++){
        float uv = up[t];
        float acc = 0.f;
        #pragma unroll
        for (int n = 0; n < 16; n++){
            float nr = fmaf(dar[n], sr[n], uv);
            nr = fmaf(-dai[n], si[n], nr);
            float ni = dar[n]*si[n];
            ni = fmaf(dai[n], sr[n], ni);
            sr[n] = nr; si[n] = ni;
            acc = fmaf(cfr[n], nr, acc);
            acc = fmaf(-cfi[n], ni, acc);
        }
        acc += __shfl_xor(acc, 1);
        up[t] = fmaf(Dh, uv, acc);
    }
    __syncthreads();
    for (int r = 0; r < 8; r++){
        int qq = r*512 + tx;
        int bq2 = qq >> 10, pq = qq & 1023;
        int p = pq*4;
        int base = bq2*4160 + (p >> 6)*65 + (p & 63);
        float4 v = {us[base], us[base+1], us[base+2], us[base+3]};
        *(float4*)(out + ((size_t)((b0+bq2)*256 + h))*4096 + p) = v;
    }
}

// ---------------------------------------------------------------------------
extern "C" void kernel_launch(void* const* d_in, const int* in_sizes, int n_in,
                              void* d_out, int out_size, void* d_ws, size_t ws_size,
                              hipStream_t stream)
{
    (void)in_sizes; (void)n_in; (void)out_size; (void)ws_size;
    const float* x     = (const float*)d_in[0];
    const float* w1    = (const float*)d_in[1];
    const float* b1    = (const float*)d_in[2];
    const float* w2    = (const float*)d_in[3];
    const float* b2    = (const float*)d_in[4];
    const float* w3    = (const float*)d_in[5];
    const float* b3    = (const float*)d_in[6];
    const float* w4    = (const float*)d_in[7];
    const float* b4    = (const float*)d_in[8];
    const float* gamma = (const float*)d_in[9];
    const float* beta  = (const float*)d_in[10];
    const float* cw    = (const float*)d_in[11];
    const float* cb    = (const float*)d_in[12];
    const float* Are   = (const float*)d_in[13];
    const float* Aim   = (const float*)d_in[14];
    const float* logdt = (const float*)d_in[15];
    const float* Cre   = (const float*)d_in[16];
    const float* Cim   = (const float*)d_in[17];
    const float* Dp    = (const float*)d_in[18];
    float* out = (float*)d_out;

    char* ws = (char*)d_ws;
    ushort_t* zT = (ushort_t*)ws;                // 33,554,432 B  bf16 z^T [b][p][c]
    float* u     = (float*)(ws + 33554432);      // 33,554,432 B  f32 u
    float* S     = (float*)ws;                   // alias zT after conv consumes it
    char* mscB   = ws + 67108864;
    float* stats   = (float*)(mscB + 0);         // 1024 f32
    float* scale   = (float*)(mscB + 4096);      // 512
    float* shift   = (float*)(mscB + 6144);      // 512
    float* constb  = (float*)(mscB + 8192);      // 256
    ushort_t* Wfbf = (ushort_t*)(mscB + 9216);   // 262,144 B (256x512 bf16)
    float* ssm     = (float*)(mscB + 271360);    // 196,608 B
    ushort_t* Wt   = (ushort_t*)(mscB + 467968); // 262,144 B (8x128x128 bf16)
    float* dAr  = ssm;
    float* dAi  = ssm + 8192;
    float* dATr = ssm + 16384;
    float* dATi = ssm + 24576;
    float* cfr  = ssm + 32768;
    float* cfi  = ssm + 40960;

    hipMemsetAsync(stats, 0, 1024*sizeof(float), stream);
    k_wprep<<<128, 256, 0, stream>>>(w1, w2, w3, w4, Wt);
    k_deconv<<<512, 256, 0, stream>>>(x, Wt, b1, b2, b3, b4, zT);
    k_stats<<<256, 256, 0, stream>>>(zT, stats);
    k_bnstats<<<1, 512, 0, stream>>>(stats, gamma, beta, scale, shift);
    k_fold<<<256, 256, 0, stream>>>(cw, cb, scale, shift, Wfbf, constb);
    k_conv<<<512, 256, 0, stream>>>(zT, Wfbf, constb, u);
    k_ssmprep<<<32, 256, 0, stream>>>(Are, Aim, logdt, Cre, Cim, ssm);
    k_scan1<<<512, 256, 0, stream>>>(u, dAr, dAi, S);
    k_scan2<<<256, 256, 0, stream>>>(S, dATr, dATi);
    k_scan3<<<512, 512, 0, stream>>>(u, S, dAr, dAi, cfr, cfi, Dp, out);
}

// Round 12
// 219.822 us; speedup vs baseline: 2.5241x; 1.2882x over previous
//
#include <hip/hip_runtime.h>
#include <hip/hip_bf16.h>

typedef unsigned short ushort_t;
typedef unsigned int uint_t;
typedef __attribute__((ext_vector_type(8))) short bf16x8;
typedef __attribute__((ext_vector_type(4))) float f32x4;

#define LEAKYC 0.3f
#define BNEPS 1e-5f

// sizes: B=8, CIN=128, LIN=2048, LOUT=4096, CMID=512, DM=256, NST=32

__device__ __forceinline__ ushort_t f2bf(float f){
    uint_t x = __float_as_uint(f);
    uint_t r = x + 0x7fffu + ((x >> 16) & 1u);
    return (ushort_t)(r >> 16);
}
__device__ __forceinline__ float bf2f(ushort_t u){
    return __uint_as_float(((uint_t)u) << 16);
}
__device__ __forceinline__ uint_t pack2(float a, float b){
    return (uint_t)f2bf(a) | ((uint_t)f2bf(b) << 16);
}
__device__ __forceinline__ float lrelu(float v){
    return (v >= 0.f) ? v : LEAKYC*v;
}

// ---------------------------------------------------------------------------
// Kernel 0: weight prep — fp32 w[d][i][o][tap] -> bf16 Wt[(d*2+tap)][o][i]
// ---------------------------------------------------------------------------
__global__ __launch_bounds__(256) void k_wprep(
    const float* __restrict__ w1, const float* __restrict__ w2,
    const float* __restrict__ w3, const float* __restrict__ w4,
    ushort_t* __restrict__ Wt)
{
    int g = blockIdx.x*256 + threadIdx.x;    // = i*256 + o*2 + t
    int i = g >> 8, o = (g >> 1) & 127, t = g & 1;
    int ob = (t*128 + o)*128 + i;
    Wt[ob]             = f2bf(w1[g]);
    Wt[2*16384 + ob]   = f2bf(w2[g]);
    Wt[4*16384 + ob]   = f2bf(w3[g]);
    Wt[6*16384 + ob]   = f2bf(w4[g]);
}

// ---------------------------------------------------------------------------
// Kernel 1: deconv via bf16 MFMA  (unchanged, verified round 11)
// ---------------------------------------------------------------------------
__global__ __launch_bounds__(256) void k_deconv(
    const float* __restrict__ x, const ushort_t* __restrict__ Wt,
    const float* __restrict__ b1, const float* __restrict__ b2,
    const float* __restrict__ b3, const float* __restrict__ b4,
    ushort_t* __restrict__ zT)
{
    __shared__ float xs[128*41];
    const int tx = threadIdx.x, lane = tx & 63;
    const int d  = tx >> 6;
    const int bb = blockIdx.x >> 6, lt = blockIdx.x & 63;
    const int l0 = lt*32;
    const float* xb = x + (size_t)bb*262144;

    for (int it = 0; it < 16; it++){
        int idx = it*256 + tx;
        int i = idx >> 5, lc = idx & 31;
        xs[i*41 + 4 + lc] = xb[i*2048 + l0 + lc];
    }
    for (int it = 0; it < 2; it++){
        int idx = it*256 + tx;
        int i = idx >> 2, dl = idx & 3;
        int l = l0 - 4 + dl;
        xs[i*41 + dl] = (l >= 0) ? xb[i*2048 + l] : 0.f;
    }
    __syncthreads();

    const int r = lane & 15, q = lane >> 4;
    const int S  = (d==0) ? 0 : (1 << (d-1));
    const int NT = (d==0) ? 4 : 2;
    const float* bd = (d==0) ? b1 : (d==1) ? b2 : (d==2) ? b3 : b4;
    const size_t zrowb = (size_t)bb*4096 + (size_t)lt*64;

    for (int tt = 0; tt < NT; tt++){
        const int ob   = (d==0) ? ((tt&1)*64) : tt*64;
        const int tapA = (d==0) ? (tt>>1) : 0;
        const int nseg = (d==0) ? 1 : 2;
        f32x4 acc[4][2] = {};
        for (int sg = 0; sg < nseg; sg++){
            const int tap = (d==0) ? tapA : sg;
            const int sh  = (sg==1) ? S : 0;
            const ushort_t* Arow = Wt + ((size_t)((d*2+tap)*128 + ob + r))*128 + q*8;
            const float* xcolb = xs + 4 + r - sh;
            #pragma unroll
            for (int kc = 0; kc < 4; kc++){
                uint4 a4[4];
                #pragma unroll
                for (int mi = 0; mi < 4; mi++)
                    a4[mi] = *(const uint4*)(Arow + mi*2048 + kc*32);
                const int kb = kc*32 + q*8;
                uint_t bfr[2][4];
                #pragma unroll
                for (int nj = 0; nj < 2; nj++){
                    const float* xc = xcolb + nj*16;
                    #pragma unroll
                    for (int kk = 0; kk < 4; kk++){
                        float e0 = xc[(kb + 2*kk)*41];
                        float e1 = xc[(kb + 2*kk + 1)*41];
                        bfr[nj][kk] = pack2(e0, e1);
                    }
                }
                #pragma unroll
                for (int mi = 0; mi < 4; mi++){
                    #pragma unroll
                    for (int nj = 0; nj < 2; nj++){
                        acc[mi][nj] = __builtin_amdgcn_mfma_f32_16x16x32_bf16(
                            *(const bf16x8*)&a4[mi], *(const bf16x8*)bfr[nj],
                            acc[mi][nj], 0, 0, 0);
                    }
                }
            }
        }
        const int podd = (d==0 && tapA==1) ? 1 : 0;
        #pragma unroll
        for (int mi = 0; mi < 4; mi++){
            const int oo = ob + mi*16 + q*4;
            const float4 bq = *(const float4*)(bd + oo);
            const int c = d*128 + oo;
            #pragma unroll
            for (int nj = 0; nj < 2; nj++){
                f32x4 v = acc[mi][nj];
                float z0 = v[0] + bq.x, z1 = v[1] + bq.y;
                float z2 = v[2] + bq.z, z3 = v[3] + bq.w;
                if (d > 0){
                    z0 = lrelu(z0); z1 = lrelu(z1);
                    z2 = lrelu(z2); z3 = lrelu(z3);
                }
                const int lcol = nj*16 + r;
                size_t row = zrowb + 2*lcol + podd;
                uint2 pk = { pack2(z0, z1), pack2(z2, z3) };
                *(uint2*)(zT + row*512 + c) = pk;
            }
        }
    }

    if (d > 0){
        #pragma unroll
        for (int rep = 0; rep < 8; rep++){
            int idx = rep*64 + lane;
            int li = idx >> 4, cg = (idx & 15)*8;
            float4 f0 = *(const float4*)(bd + cg);
            float4 f1 = *(const float4*)(bd + cg + 4);
            uint4 pkv = { pack2(lrelu(f0.x), lrelu(f0.y)),
                          pack2(lrelu(f0.z), lrelu(f0.w)),
                          pack2(lrelu(f1.x), lrelu(f1.y)),
                          pack2(lrelu(f1.z), lrelu(f1.w)) };
            size_t row = zrowb + 2*li + 1;
            *(uint4*)(zT + row*512 + d*128 + cg) = pkv;
        }
    }
}

// ---------------------------------------------------------------------------
// Kernel 1b: BN stats from zT (bf16)  (unchanged, verified)
// ---------------------------------------------------------------------------
__global__ __launch_bounds__(256) void k_stats(
    const ushort_t* __restrict__ zT, float* __restrict__ stats)
{
    const int tx = threadIdx.x;
    const int c = 2*tx;
    const ushort_t* base = zT + (size_t)blockIdx.x*128*512 + c;
    float s0=0.f, s1=0.f, q0=0.f, q1=0.f;
    for (int rr = 0; rr < 128; rr++){
        ushort2 v = *(const ushort2*)(base + (size_t)rr*512);
        float f0 = bf2f(v.x), f1 = bf2f(v.y);
        s0 += f0; s1 += f1;
        q0 += f0*f0; q1 += f1*f1;
    }
    atomicAdd(&stats[c],       s0);
    atomicAdd(&stats[c+1],     s1);
    atomicAdd(&stats[512+c],   q0);
    atomicAdd(&stats[512+c+1], q1);
}

// ---------------------------------------------------------------------------
// Kernel 2a: BN scale/shift  (unchanged, verified)
// ---------------------------------------------------------------------------
__global__ void k_bnstats(const float* __restrict__ stats,
                          const float* __restrict__ gamma, const float* __restrict__ beta,
                          float* __restrict__ scale, float* __restrict__ shift)
{
    int c = threadIdx.x;
    const float N = 32768.f;
    float mean = stats[c] / N;
    float var  = stats[512 + c] / N - mean*mean;
    var = fmaxf(var, 0.f);
    float sc = gamma[c & 127] * rsqrtf(var + BNEPS);
    scale[c] = sc;
    shift[c] = beta[c & 127] - mean * sc;
}

// ---------------------------------------------------------------------------
// Kernel 2b: fold BN into conv weights  (unchanged, verified)
// ---------------------------------------------------------------------------
__global__ __launch_bounds__(256) void k_fold(
    const float* __restrict__ cw, const float* __restrict__ cb,
    const float* __restrict__ scale, const float* __restrict__ shift,
    ushort_t* __restrict__ Wfbf, float* __restrict__ constb)
{
    __shared__ float red[256];
    int m = blockIdx.x;
    int tx = threadIdx.x;
    int c1 = tx, c2 = tx + 256;
    float wv1 = cw[m*512 + c1], wv2 = cw[m*512 + c2];
    Wfbf[m*512 + c1] = f2bf(wv1 * scale[c1]);
    Wfbf[m*512 + c2] = f2bf(wv2 * scale[c2]);
    red[tx] = wv1*shift[c1] + wv2*shift[c2];
    __syncthreads();
    for (int s = 128; s > 0; s >>= 1){
        if (tx < s) red[tx] += red[tx + s];
        __syncthreads();
    }
    if (tx == 0) constb[m] = cb[m] + red[0];
}

// ---------------------------------------------------------------------------
// Kernel 3: 1x1 conv GEMM via bf16 MFMA  (unchanged, verified)
// ---------------------------------------------------------------------------
__global__ __launch_bounds__(256) void k_conv(
    const ushort_t* __restrict__ zT, const ushort_t* __restrict__ Wfbf,
    const float* __restrict__ constb, float* __restrict__ u)
{
    __shared__ ushort_t As[128*40];
    __shared__ ushort_t Bs[128*40];
    const int tx  = threadIdx.x;
    const int bid = blockIdx.x;
    const int pt = bid & 31, b = (bid >> 5) & 7, mt = bid >> 8;
    const int m0 = mt*128, pbase = pt*128;
    const int lane = tx & 63, wvid = tx >> 6;
    const int r = lane & 15, q = lane >> 4;
    const int wm = (wvid & 1)*64, wp = (wvid >> 1)*64;

    const int smm = tx >> 1;
    const int skk = (tx & 1) * 16;

    const ushort_t* gA = Wfbf + (m0 + smm)*512 + skk;
    const ushort_t* gB = zT + ((size_t)(b*4096 + pbase + smm))*512 + skk;

    f32x4 acc[4][4] = {};
    uint4 ra0, ra1, rb0, rb1;
    ra0 = *(const uint4*)(gA);     ra1 = *(const uint4*)(gA + 8);
    rb0 = *(const uint4*)(gB);     rb1 = *(const uint4*)(gB + 8);

    for (int ct = 0; ct < 16; ct++){
        __syncthreads();
        *(uint4*)(&As[smm*40 + skk])     = ra0;
        *(uint4*)(&As[smm*40 + skk + 8]) = ra1;
        *(uint4*)(&Bs[smm*40 + skk])     = rb0;
        *(uint4*)(&Bs[smm*40 + skk + 8]) = rb1;
        __syncthreads();
        if (ct < 15){
            const ushort_t* gA2 = gA + (ct+1)*32;
            const ushort_t* gB2 = gB + (ct+1)*32;
            ra0 = *(const uint4*)(gA2); ra1 = *(const uint4*)(gA2 + 8);
            rb0 = *(const uint4*)(gB2); rb1 = *(const uint4*)(gB2 + 8);
        }
        bf16x8 af[4], bfv[4];
        #pragma unroll
        for (int f = 0; f < 4; f++){
            af[f]  = *(const bf16x8*)(&As[(wm + f*16 + r)*40 + 8*q]);
            bfv[f] = *(const bf16x8*)(&Bs[(wp + f*16 + r)*40 + 8*q]);
        }
        #pragma unroll
        for (int i = 0; i < 4; i++){
            #pragma unroll
            for (int j = 0; j < 4; j++){
                acc[i][j] = __builtin_amdgcn_mfma_f32_16x16x32_bf16(af[i], bfv[j], acc[i][j], 0, 0, 0);
            }
        }
    }
    #pragma unroll
    for (int i = 0; i < 4; i++){
        #pragma unroll
        for (int t = 0; t < 4; t++){
            int m = m0 + wm + i*16 + 4*q + t;
            float cbv = constb[m];
            float* up = u + ((size_t)(b*256 + m))*4096 + pbase + wp + r;
            #pragma unroll
            for (int j = 0; j < 4; j++)
                up[j*16] = acc[i][j][t] + cbv;
        }
    }
}

// ---------------------------------------------------------------------------
// Kernel 4: SSM parameter prep  (unchanged, verified)
// ---------------------------------------------------------------------------
__global__ void k_ssmprep(const float* __restrict__ Are, const float* __restrict__ Aim,
                          const float* __restrict__ logdt,
                          const float* __restrict__ Cre, const float* __restrict__ Cim,
                          float* __restrict__ ssm)
{
    int g = blockIdx.x*256 + threadIdx.x;
    if (g >= 8192) return;
    int h = g >> 5;
    float ar = Are[g], ai = Aim[g];
    float dt = expf(logdt[h]);
    float ea = expf(dt*ar);
    float dAr = ea * cosf(dt*ai);
    float dAi = ea * sinf(dt*ai);
    float nr = dAr - 1.f, ni = dAi;
    float den = ar*ar + ai*ai;
    float dBr = (nr*ar + ni*ai) / den;
    float dBi = (ni*ar - nr*ai) / den;
    float cr = Cre[g]*dBr - Cim[g]*dBi;
    float ci = Cre[g]*dBi + Cim[g]*dBr;
    float tr = dAr, ti = dAi;
    #pragma unroll
    for (int k = 0; k < 6; k++){
        float t2r = tr*tr - ti*ti;
        float t2i = 2.f*tr*ti;
        tr = t2r; ti = t2i;
    }
    ssm[g]           = dAr;
    ssm[8192  + g]   = dAi;
    ssm[16384 + g]   = tr;
    ssm[24576 + g]   = ti;
    ssm[32768 + g]   = 2.f*cr;
    ssm[40960 + g]   = 2.f*ci;
}

// ---------------------------------------------------------------------------
// Kernel 4b: per-h scan matrices (bf16):
//  Wm[h][j][tau]: j=2n -> Re(dA^(63-tau)), j=2n+1 -> Im   (end-state GEMM B)
//  TVm[h][t][k]:  k<64: tau=k -> causal Toeplitz K[t-tau] (+D on diag)
//                 k>=64: j=k-64 -> V[t][j] carry matrix
// ---------------------------------------------------------------------------
__global__ __launch_bounds__(64) void k_matprep(
    const float* __restrict__ ssm, const float* __restrict__ Dp,
    ushort_t* __restrict__ Wm, ushort_t* __restrict__ TVm)
{
    __shared__ float pr[32*65];
    __shared__ float pi[32*65];
    __shared__ float Ks[64];
    const int h = blockIdx.x, tx = threadIdx.x;
    if (tx < 32){
        const int g = h*32 + tx;
        const float ar = ssm[g], ai = ssm[8192 + g];
        float xr = 1.f, xi = 0.f;
        for (int p = 0; p < 65; p++){
            pr[tx*65 + p] = xr; pi[tx*65 + p] = xi;
            float nx = xr*ar - xi*ai;
            float ny = xr*ai + xi*ar;
            xr = nx; xi = ny;
        }
    }
    __syncthreads();
    {
        float s = 0.f;
        for (int n = 0; n < 32; n++){
            const int g = h*32 + n;
            s += ssm[32768 + g]*pr[n*65 + tx] - ssm[40960 + g]*pi[n*65 + tx];
        }
        Ks[tx] = s;
    }
    __syncthreads();
    const float Dh = Dp[h];
    {   // Wm row j = tx
        const int n = tx >> 1;
        const int isim = tx & 1;
        ushort_t* wrow = Wm + (size_t)h*4096 + tx*64;
        for (int tau = 0; tau < 64; tau++){
            float v = isim ? pi[n*65 + 63 - tau] : pr[n*65 + 63 - tau];
            wrow[tau] = f2bf(v);
        }
    }
    {   // TVm row t = tx
        ushort_t* trow = TVm + (size_t)h*8192 + tx*128;
        for (int k = 0; k < 64; k++){
            float v = (tx >= k) ? (Ks[tx - k] + ((tx == k) ? Dh : 0.f)) : 0.f;
            trow[k] = f2bf(v);
        }
        for (int j = 0; j < 64; j++){
            const int n = j >> 1;
            const int g = h*32 + n;
            const float cfr = ssm[32768 + g], cfi = ssm[40960 + g];
            const float P = pr[n*65 + tx + 1], Q = pi[n*65 + tx + 1];
            float v = (j & 1) ? -(cfr*Q + cfi*P) : (cfr*P - cfi*Q);
            trow[64 + j] = f2bf(v);
        }
    }
}

// ---------------------------------------------------------------------------
// Kernel 5: chunk end-states via MFMA: S[bc][j] = sum_tau U[bc][tau] Wm[h][j][tau]
// grid 512 = h(256) x bhalf(2), 256 threads = 4 waves (64 rows each)
// ---------------------------------------------------------------------------
__global__ __launch_bounds__(256) void k_sgemm1(
    const float* __restrict__ u, const ushort_t* __restrict__ Wm,
    ushort_t* __restrict__ S)
{
    __shared__ ushort_t Ul[256*72];   // 36864 B
    __shared__ ushort_t Wl[64*72];    // 9216 B
    const int tx = threadIdx.x;
    const int h = blockIdx.x >> 1, bh = (blockIdx.x & 1)*4;
    for (int rr = 0; rr < 16; rr++){
        int idx = rr*256 + tx;
        int j = idx >> 6, col = idx & 63;
        Wl[j*72 + col] = Wm[(size_t)h*4096 + idx];
    }
    for (int rr = 0; rr < 16; rr++){
        int idx = rr*256 + tx;
        int row = idx >> 4, fi = idx & 15;
        int bb = row >> 6, cc = row & 63;
        const float* up = u + ((size_t)((bh+bb)*256 + h))*4096 + cc*64 + fi*4;
        float4 v = *(const float4*)up;
        uint2 pk = { pack2(v.x, v.y), pack2(v.z, v.w) };
        *(uint2*)&Ul[row*72 + fi*4] = pk;
    }
    __syncthreads();
    const int lane = tx & 63, w = tx >> 6;
    const int r = lane & 15, q = lane >> 4;
    const int wm = w*64;
    f32x4 acc[4][4] = {};
    #pragma unroll
    for (int kc = 0; kc < 2; kc++){
        bf16x8 af[4], bv[4];
        #pragma unroll
        for (int mi = 0; mi < 4; mi++)
            af[mi] = *(const bf16x8*)&Ul[(wm + mi*16 + r)*72 + kc*32 + q*8];
        #pragma unroll
        for (int nj = 0; nj < 4; nj++)
            bv[nj] = *(const bf16x8*)&Wl[(nj*16 + r)*72 + kc*32 + q*8];
        #pragma unroll
        for (int mi = 0; mi < 4; mi++){
            #pragma unroll
            for (int nj = 0; nj < 4; nj++){
                acc[mi][nj] = __builtin_amdgcn_mfma_f32_16x16x32_bf16(af[mi], bv[nj], acc[mi][nj], 0, 0, 0);
            }
        }
    }
    #pragma unroll
    for (int mi = 0; mi < 4; mi++){
        #pragma unroll
        for (int tt = 0; tt < 4; tt++){
            int row = wm + mi*16 + 4*q + tt;
            int bb = row >> 6, cc = row & 63;
            ushort_t* sp = S + ((size_t)((bh+bb)*256 + h))*4096 + cc*64;
            #pragma unroll
            for (int nj = 0; nj < 4; nj++)
                sp[nj*16 + r] = f2bf(acc[mi][nj][tt]);
        }
    }
}

// ---------------------------------------------------------------------------
// Kernel 6: scan pass 2 — sequential carry combine over chunks (bf16 S)
// thread = (b,h,n); S := carry-in
// ---------------------------------------------------------------------------
__global__ __launch_bounds__(256) void k_scan2(
    ushort_t* __restrict__ S, const float* __restrict__ dATr_, const float* __restrict__ dATi_)
{
    int g = blockIdx.x*256 + threadIdx.x;
    int n = g & 31, h = (g >> 5) & 255, b = g >> 13;
    float ar = dATr_[h*32 + n], ai = dATi_[h*32 + n];
    float cr = 0.f, ci = 0.f;
    uint_t* p = (uint_t*)S + (size_t)(b*256 + h)*2048 + n;
    for (int c = 0; c < 64; c++){
        uint_t t = *p;
        float tr = bf2f((ushort_t)(t & 0xffff));
        float ti = bf2f((ushort_t)(t >> 16));
        *p = pack2(cr, ci);
        float ncr = fmaf(ar, cr, tr);
        ncr = fmaf(-ai, ci, ncr);
        float nci = fmaf(ai, cr, ti);
        nci = fmaf(ar, ci, nci);
        cr = ncr; ci = nci;
        p += 32;   // 64 ushorts = 32 uints per chunk
    }
}

// ---------------------------------------------------------------------------
// Kernel 7: outputs via MFMA: Y[bc][t] = U·T^T + Sin·V^T  (D folded into T diag)
// A = [U | Sin] (256 x 128), B = TVm[h] as [t][k], K=128 in 2 staged halves
// ---------------------------------------------------------------------------
__global__ __launch_bounds__(256) void k_sgemm2(
    const float* __restrict__ u, const ushort_t* __restrict__ S,
    const ushort_t* __restrict__ TVm, float* __restrict__ out)
{
    __shared__ ushort_t Al[256*72];    // 36864 B (reused per K-half)
    __shared__ ushort_t Bl[64*136];    // 17408 B
    const int tx = threadIdx.x;
    const int h = blockIdx.x >> 1, bh = (blockIdx.x & 1)*4;
    for (int rr = 0; rr < 32; rr++){
        int idx = rr*256 + tx;              // 8192
        int t = idx >> 7, k = idx & 127;
        Bl[t*136 + k] = TVm[(size_t)h*8192 + idx];
    }
    const int lane = tx & 63, w = tx >> 6;
    const int r = lane & 15, q = lane >> 4;
    const int wm = w*64;
    f32x4 acc[4][4] = {};
    #pragma unroll
    for (int half = 0; half < 2; half++){
        __syncthreads();
        if (half == 0){
            for (int rr = 0; rr < 16; rr++){
                int idx = rr*256 + tx;
                int row = idx >> 4, fi = idx & 15;
                int bb = row >> 6, cc = row & 63;
                const float* up = u + ((size_t)((bh+bb)*256 + h))*4096 + cc*64 + fi*4;
                float4 v = *(const float4*)up;
                uint2 pk = { pack2(v.x, v.y), pack2(v.z, v.w) };
                *(uint2*)&Al[row*72 + fi*4] = pk;
            }
        } else {
            for (int rr = 0; rr < 16; rr++){
                int idx = rr*256 + tx;
                int row = idx >> 4, fi = idx & 15;
                int bb = row >> 6, cc = row & 63;
                const ushort_t* sp = S + ((size_t)((bh+bb)*256 + h))*4096 + cc*64 + fi*4;
                *(uint2*)&Al[row*72 + fi*4] = *(const uint2*)sp;
            }
        }
        __syncthreads();
        #pragma unroll
        for (int kc = 0; kc < 2; kc++){
            bf16x8 af[4], bv[4];
            #pragma unroll
            for (int mi = 0; mi < 4; mi++)
                af[mi] = *(const bf16x8*)&Al[(wm + mi*16 + r)*72 + kc*32 + q*8];
            #pragma unroll
            for (int nj = 0; nj < 4; nj++)
                bv[nj] = *(const bf16x8*)&Bl[(nj*16 + r)*136 + half*64 + kc*32 + q*8];
            #pragma unroll
            for (int mi = 0; mi < 4; mi++){
                #pragma unroll
                for (int nj = 0; nj < 4; nj++){
                    acc[mi][nj] = __builtin_amdgcn_mfma_f32_16x16x32_bf16(af[mi], bv[nj], acc[mi][nj], 0, 0, 0);
                }
            }
        }
    }
    #pragma unroll
    for (int mi = 0; mi < 4; mi++){
        #pragma unroll
        for (int tt = 0; tt < 4; tt++){
            int row = wm + mi*16 + 4*q + tt;
            int bb = row >> 6, cc = row & 63;
            float* op = out + ((size_t)((bh+bb)*256 + h))*4096 + cc*64;
            #pragma unroll
            for (int nj = 0; nj < 4; nj++)
                op[nj*16 + r] = acc[mi][nj][tt];
        }
    }
}

// ---------------------------------------------------------------------------
extern "C" void kernel_launch(void* const* d_in, const int* in_sizes, int n_in,
                              void* d_out, int out_size, void* d_ws, size_t ws_size,
                              hipStream_t stream)
{
    (void)in_sizes; (void)n_in; (void)out_size; (void)ws_size;
    const float* x     = (const float*)d_in[0];
    const float* w1    = (const float*)d_in[1];
    const float* b1    = (const float*)d_in[2];
    const float* w2    = (const float*)d_in[3];
    const float* b2    = (const float*)d_in[4];
    const float* w3    = (const float*)d_in[5];
    const float* b3    = (const float*)d_in[6];
    const float* w4    = (const float*)d_in[7];
    const float* b4    = (const float*)d_in[8];
    const float* gamma = (const float*)d_in[9];
    const float* beta  = (const float*)d_in[10];
    const float* cw    = (const float*)d_in[11];
    const float* cb    = (const float*)d_in[12];
    const float* Are   = (const float*)d_in[13];
    const float* Aim   = (const float*)d_in[14];
    const float* logdt = (const float*)d_in[15];
    const float* Cre   = (const float*)d_in[16];
    const float* Cim   = (const float*)d_in[17];
    const float* Dp    = (const float*)d_in[18];
    float* out = (float*)d_out;

    char* ws = (char*)d_ws;
    ushort_t* zT = (ushort_t*)ws;                 // 32 MB, dead after k_conv
    float* u     = (float*)(ws + 33554432);       // 32 MB f32
    // zT region reuse (all written AFTER k_conv completes):
    ushort_t* S   = (ushort_t*)ws;                // 16 MB bf16 chunk states / carries
    ushort_t* Wm  = (ushort_t*)(ws + 16777216);   // 2 MB
    ushort_t* TVm = (ushort_t*)(ws + 18874368);   // 4 MB (ends 22.0 MB < 32 MB)
    char* mscB   = ws + 67108864;
    float* stats   = (float*)(mscB + 0);          // 1024 f32
    float* scale   = (float*)(mscB + 4096);
    float* shift   = (float*)(mscB + 6144);
    float* constb  = (float*)(mscB + 8192);
    ushort_t* Wfbf = (ushort_t*)(mscB + 9216);    // 262144 B
    float* ssm     = (float*)(mscB + 271360);     // 196608 B
    ushort_t* Wt   = (ushort_t*)(mscB + 467968);  // 262144 B
    float* dATr = ssm + 16384;
    float* dATi = ssm + 24576;

    hipMemsetAsync(stats, 0, 1024*sizeof(float), stream);
    k_wprep<<<128, 256, 0, stream>>>(w1, w2, w3, w4, Wt);
    k_deconv<<<512, 256, 0, stream>>>(x, Wt, b1, b2, b3, b4, zT);
    k_stats<<<256, 256, 0, stream>>>(zT, stats);
    k_bnstats<<<1, 512, 0, stream>>>(stats, gamma, beta, scale, shift);
    k_fold<<<256, 256, 0, stream>>>(cw, cb, scale, shift, Wfbf, constb);
    k_conv<<<512, 256, 0, stream>>>(zT, Wfbf, constb, u);
    k_ssmprep<<<32, 256, 0, stream>>>(Are, Aim, logdt, Cre, Cim, ssm);
    k_matprep<<<256, 64, 0, stream>>>(ssm, Dp, Wm, TVm);
    k_sgemm1<<<512, 256, 0, stream>>>(u, Wm, S);
    k_scan2<<<256, 256, 0, stream>>>(S, dATr, dATi);
    k_sgemm2<<<512, 256, 0, stream>>>(u, S, TVm, out);
}